// Round 1
// baseline (1342.585 us; speedup 1.0000x reference)
//
#include <hip/hip_runtime.h>

#define NN 50000      // nodes
#define NE 800000     // edges
#define FD 128        // input feature dim
#define HD 256        // hidden dim
#define AD 32         // action dim
#define GN 50         // graphs
#define BN_EPS 1e-5f

// ---------------- degree / CSR build ----------------

__global__ void k_deg(const int* __restrict__ dst, int* __restrict__ counts) {
    int e = blockIdx.x * blockDim.x + threadIdx.x;
    if (e < NE) atomicAdd(&counts[dst[e]], 1);
}

__global__ void k_dis(const int* __restrict__ counts, float* __restrict__ dis) {
    int i = blockIdx.x * blockDim.x + threadIdx.x;
    if (i < NN) dis[i] = rsqrtf(1.0f + (float)counts[i]);
}

__global__ void k_scan1(const int* __restrict__ counts, int* __restrict__ rowptr,
                        int* __restrict__ bsum) {
    __shared__ int s[1024];
    int t = threadIdx.x;
    int i = blockIdx.x * 1024 + t;
    int v = (i < NN) ? counts[i] : 0;
    s[t] = v;
    __syncthreads();
    for (int off = 1; off < 1024; off <<= 1) {
        int u = (t >= off) ? s[t - off] : 0;
        __syncthreads();
        s[t] += u;
        __syncthreads();
    }
    if (i < NN) rowptr[i + 1] = s[t];
    if (t == 1023) bsum[blockIdx.x] = s[1023];
}

__global__ void k_scan2(int* __restrict__ bsum, int* __restrict__ rowptr, int nblk) {
    if (threadIdx.x == 0 && blockIdx.x == 0) {
        int run = 0;
        for (int b = 0; b < nblk; ++b) { int t = bsum[b]; bsum[b] = run; run += t; }
        rowptr[0] = 0;
    }
}

__global__ void k_scan3(int* __restrict__ rowptr, const int* __restrict__ bsum) {
    int i = blockIdx.x * blockDim.x + threadIdx.x;
    if (i < NN) rowptr[i + 1] += bsum[i >> 10];
}

__global__ void k_csr(const int* __restrict__ src, const int* __restrict__ dst,
                      const int* __restrict__ rowptr, int* __restrict__ fill,
                      const float* __restrict__ dis,
                      int* __restrict__ csr_src, float* __restrict__ csr_w) {
    int e = blockIdx.x * blockDim.x + threadIdx.x;
    if (e < NE) {
        int d = dst[e];
        int s = src[e];
        int p = rowptr[d] + atomicAdd(&fill[d], 1);
        csr_src[p] = s;
        csr_w[p] = dis[s] * dis[d];
    }
}

// ---------------- fp32 tiled GEMM: C[NN,HD] = A[NN,K] @ B[K,HD] ----------------

__global__ __launch_bounds__(256) void k_mm(const float* __restrict__ A,
                                            const float* __restrict__ B,
                                            float* __restrict__ C, int K) {
    __shared__ float As[16][68];   // transposed: As[k][row]
    __shared__ float Bs[16][68];
    int t = threadIdx.x;
    int tx = t & 15, ty = t >> 4;
    int rowBase = blockIdx.x * 64;
    int colBase = blockIdx.y * 64;
    float acc[4][4] = {};
    int ar  = t >> 2;          // 0..63 row within tile
    int akq = (t & 3) * 4;     // k offset 0,4,8,12
    int bkk = t >> 4;          // 0..15
    int bc  = (t & 15) * 4;    // 0..60

    for (int k0 = 0; k0 < K; k0 += 16) {
        int arow = rowBase + ar;
        float4 av = make_float4(0.f, 0.f, 0.f, 0.f);
        if (arow < NN) av = *(const float4*)&A[(size_t)arow * K + k0 + akq];
        As[akq + 0][ar] = av.x;
        As[akq + 1][ar] = av.y;
        As[akq + 2][ar] = av.z;
        As[akq + 3][ar] = av.w;
        float4 bv = *(const float4*)&B[(size_t)(k0 + bkk) * HD + colBase + bc];
        *(float4*)&Bs[bkk][bc] = bv;
        __syncthreads();
#pragma unroll
        for (int kk = 0; kk < 16; ++kk) {
            float4 a4 = *(const float4*)&As[kk][ty * 4];
            float4 b4 = *(const float4*)&Bs[kk][tx * 4];
            float a[4] = {a4.x, a4.y, a4.z, a4.w};
            float b[4] = {b4.x, b4.y, b4.z, b4.w};
#pragma unroll
            for (int i = 0; i < 4; ++i)
#pragma unroll
                for (int j = 0; j < 4; ++j)
                    acc[i][j] = fmaf(a[i], b[j], acc[i][j]);
        }
        __syncthreads();
    }
#pragma unroll
    for (int i = 0; i < 4; ++i) {
        int row = rowBase + ty * 4 + i;
        if (row < NN) {
            float4 v = make_float4(acc[i][0], acc[i][1], acc[i][2], acc[i][3]);
            *(float4*)&C[(size_t)row * HD + colBase + tx * 4] = v;
        }
    }
}

// ---------------- GCN aggregate + bias + relu ----------------
// out[n,j] = relu( hw[n,j]/deg_n + b[j] + sum_{e: dst==n} hw[src_e, j] * w_e )

__global__ __launch_bounds__(256) void k_agg(const float* __restrict__ hw,
                                             const int* __restrict__ rowptr,
                                             const int* __restrict__ csr_src,
                                             const float* __restrict__ csr_w,
                                             const float* __restrict__ dis,
                                             const float* __restrict__ bias,
                                             float* __restrict__ out) {
    int n = blockIdx.x;
    int j = threadIdx.x;
    float d = dis[n];
    float acc = fmaf(hw[(size_t)n * HD + j], d * d, bias[j]);
    int e0 = rowptr[n], e1 = rowptr[n + 1];
    for (int e = e0; e < e1; ++e) {
        int s = csr_src[e];
        acc = fmaf(hw[(size_t)s * HD + j], csr_w[e], acc);
    }
    out[(size_t)n * HD + j] = fmaxf(acc, 0.0f);
}

// ---------------- batchnorm over NN rows ----------------

__global__ __launch_bounds__(256) void k_stats(const float* __restrict__ h,
                                               float* __restrict__ stats) {
    int j = threadIdx.x;
    int rows_per = (NN + gridDim.x - 1) / gridDim.x;
    int r0 = blockIdx.x * rows_per;
    int r1 = min(r0 + rows_per, NN);
    float s = 0.f, q = 0.f;
    for (int r = r0; r < r1; ++r) {
        float v = h[(size_t)r * HD + j];
        s += v;
        q = fmaf(v, v, q);
    }
    atomicAdd(&stats[j], s);
    atomicAdd(&stats[HD + j], q);
}

__global__ __launch_bounds__(256) void k_bn(float* __restrict__ h,
                                            const float* __restrict__ stats,
                                            const float* __restrict__ gamma,
                                            const float* __restrict__ beta) {
    size_t idx = (size_t)blockIdx.x * blockDim.x + threadIdx.x;
    if (idx < (size_t)NN * HD) {
        int j = idx & (HD - 1);
        float mu = stats[j] * (1.0f / NN);
        float var = stats[HD + j] * (1.0f / NN) - mu * mu;
        float rs = rsqrtf(var + BN_EPS);
        h[idx] = fmaf((h[idx] - mu) * rs, gamma[j], beta[j]);
    }
}

// ---------------- global mean pool ----------------

__global__ void k_gcount(const int* __restrict__ batch, int* __restrict__ gcount) {
    int i = blockIdx.x * blockDim.x + threadIdx.x;
    if (i < NN) atomicAdd(&gcount[batch[i]], 1);
}

__global__ void k_pool(const float* __restrict__ h, const int* __restrict__ batch,
                       float* __restrict__ pooled) {
    size_t idx = (size_t)blockIdx.x * blockDim.x + threadIdx.x;
    if (idx < (size_t)NN * HD) {
        int n = idx >> 8;
        int j = idx & (HD - 1);
        atomicAdd(&pooled[(size_t)batch[n] * HD + j], h[idx]);
    }
}

__global__ void k_poolfin(float* __restrict__ pooled, const int* __restrict__ gcount) {
    int idx = blockIdx.x * blockDim.x + threadIdx.x;
    if (idx < GN * HD) {
        int g = idx >> 8;
        float c = (float)max(gcount[g], 1);
        pooled[idx] /= c;
    }
}

// ---------------- MLP head ----------------

__global__ __launch_bounds__(256) void k_head1(const float* __restrict__ pooled,
                                               const float* __restrict__ actions,
                                               const float* __restrict__ fW1,
                                               const float* __restrict__ fb1,
                                               float* __restrict__ z1) {
    int g = blockIdx.x, j = threadIdx.x;
    float acc = fb1[j];
    for (int k = 0; k < HD; ++k)
        acc = fmaf(pooled[g * HD + k], fW1[k * HD + j], acc);
    for (int k = 0; k < AD; ++k)
        acc = fmaf(actions[k], fW1[(HD + k) * HD + j], acc);
    z1[g * HD + j] = fmaxf(acc, 0.f);
}

__global__ __launch_bounds__(256) void k_headbn(float* __restrict__ z1,
                                                const float* __restrict__ g3,
                                                const float* __restrict__ be3) {
    int j = threadIdx.x;
    float s = 0.f, q = 0.f;
    for (int g = 0; g < GN; ++g) {
        float v = z1[g * HD + j];
        s += v;
        q = fmaf(v, v, q);
    }
    float mu = s * (1.0f / GN);
    float var = q * (1.0f / GN) - mu * mu;
    float rs = rsqrtf(var + BN_EPS);
    float ga = g3[j], be = be3[j];
    for (int g = 0; g < GN; ++g)
        z1[g * HD + j] = fmaf((z1[g * HD + j] - mu) * rs, ga, be);
}

__global__ __launch_bounds__(128) void k_head2(const float* __restrict__ z1,
                                               const float* __restrict__ fW2,
                                               const float* __restrict__ fb2,
                                               float* __restrict__ z2) {
    int g = blockIdx.x, j = threadIdx.x;
    float acc = fb2[j];
    for (int k = 0; k < HD; ++k)
        acc = fmaf(z1[g * HD + k], fW2[k * (HD / 2) + j], acc);
    z2[g * (HD / 2) + j] = fmaxf(acc, 0.f);
}

__global__ __launch_bounds__(64) void k_head3(const float* __restrict__ z2,
                                              const float* __restrict__ fW3,
                                              const float* __restrict__ fb3,
                                              float* __restrict__ out) {
    int g = threadIdx.x;
    if (g < GN) {
        float acc = fb3[0];
        for (int k = 0; k < HD / 2; ++k)
            acc = fmaf(z2[g * (HD / 2) + k], fW3[k], acc);
        out[g] = acc;
    }
}

// ---------------- launch ----------------

static inline size_t align256(size_t x) { return (x + 255) & ~(size_t)255; }

extern "C" void kernel_launch(void* const* d_in, const int* in_sizes, int n_in,
                              void* d_out, int out_size, void* d_ws, size_t ws_size,
                              hipStream_t stream) {
    const float* x       = (const float*)d_in[0];
    const int*   ei      = (const int*)d_in[1];
    const int*   batch   = (const int*)d_in[2];
    const float* actions = (const float*)d_in[3];
    const float* W1 = (const float*)d_in[4];
    const float* b1 = (const float*)d_in[5];
    const float* W2 = (const float*)d_in[6];
    const float* b2 = (const float*)d_in[7];
    const float* W3 = (const float*)d_in[8];
    const float* b3 = (const float*)d_in[9];
    const float* g1  = (const float*)d_in[10];
    const float* be1 = (const float*)d_in[11];
    const float* g2  = (const float*)d_in[12];
    const float* be2 = (const float*)d_in[13];
    const float* g3  = (const float*)d_in[14];
    const float* be3 = (const float*)d_in[15];
    const float* fW1 = (const float*)d_in[16];
    const float* fb1 = (const float*)d_in[17];
    const float* fW2 = (const float*)d_in[18];
    const float* fb2 = (const float*)d_in[19];
    const float* fW3 = (const float*)d_in[20];
    const float* fb3 = (const float*)d_in[21];
    float* out = (float*)d_out;

    const int* esrc = ei;
    const int* edst = ei + NE;

    // workspace carve
    char* p = (char*)d_ws;
    size_t off = 0;
    auto carve = [&](size_t bytes) { void* r = p + off; off = align256(off + bytes); return r; };
    float* hw      = (float*)carve((size_t)NN * HD * 4);
    float* cur     = (float*)carve((size_t)NN * HD * 4);
    float* dis     = (float*)carve((size_t)NN * 4);
    int*   counts  = (int*)carve((size_t)NN * 4);
    int*   rowptr  = (int*)carve((size_t)(NN + 1) * 4);
    int*   fill    = (int*)carve((size_t)NN * 4);
    int*   csr_src = (int*)carve((size_t)NE * 4);
    float* csr_w   = (float*)carve((size_t)NE * 4);
    int*   bsum    = (int*)carve(64 * 4);
    float* pooled  = (float*)carve((size_t)GN * HD * 4);
    int*   gcount  = (int*)carve((size_t)GN * 4);
    float* stats   = (float*)carve(2 * HD * 4);
    float* z1      = (float*)carve((size_t)GN * HD * 4);
    float* z2      = (float*)carve((size_t)GN * (HD / 2) * 4);
    (void)ws_size;

    const int TB = 256;
    const int ebk = (NE + TB - 1) / TB;     // 3125
    const int nbk = (NN + TB - 1) / TB;     // 196
    const int scanblk = (NN + 1023) / 1024; // 49

    // degree + CSR
    hipMemsetAsync(counts, 0, (size_t)NN * 4, stream);
    k_deg<<<ebk, TB, 0, stream>>>(edst, counts);
    k_dis<<<nbk, TB, 0, stream>>>(counts, dis);
    k_scan1<<<scanblk, 1024, 0, stream>>>(counts, rowptr, bsum);
    k_scan2<<<1, 64, 0, stream>>>(bsum, rowptr, scanblk);
    k_scan3<<<nbk, TB, 0, stream>>>(rowptr, bsum);
    hipMemsetAsync(fill, 0, (size_t)NN * 4, stream);
    k_csr<<<ebk, TB, 0, stream>>>(esrc, edst, rowptr, fill, dis, csr_src, csr_w);

    dim3 mmgrid((NN + 63) / 64, HD / 64);

    // layer 1
    k_mm<<<mmgrid, TB, 0, stream>>>(x, W1, hw, FD);
    k_agg<<<NN, TB, 0, stream>>>(hw, rowptr, csr_src, csr_w, dis, b1, cur);
    hipMemsetAsync(stats, 0, 2 * HD * 4, stream);
    k_stats<<<256, TB, 0, stream>>>(cur, stats);
    k_bn<<<(NN * HD) / TB, TB, 0, stream>>>(cur, stats, g1, be1);

    // layer 2
    k_mm<<<mmgrid, TB, 0, stream>>>(cur, W2, hw, HD);
    k_agg<<<NN, TB, 0, stream>>>(hw, rowptr, csr_src, csr_w, dis, b2, cur);
    hipMemsetAsync(stats, 0, 2 * HD * 4, stream);
    k_stats<<<256, TB, 0, stream>>>(cur, stats);
    k_bn<<<(NN * HD) / TB, TB, 0, stream>>>(cur, stats, g2, be2);

    // layer 3 (relu only)
    k_mm<<<mmgrid, TB, 0, stream>>>(cur, W3, hw, HD);
    k_agg<<<NN, TB, 0, stream>>>(hw, rowptr, csr_src, csr_w, dis, b3, cur);

    // pool
    hipMemsetAsync(pooled, 0, (size_t)GN * HD * 4, stream);
    hipMemsetAsync(gcount, 0, (size_t)GN * 4, stream);
    k_gcount<<<nbk, TB, 0, stream>>>(batch, gcount);
    k_pool<<<(NN * HD) / TB, TB, 0, stream>>>(cur, batch, pooled);
    k_poolfin<<<(GN * HD + TB - 1) / TB, TB, 0, stream>>>(pooled, gcount);

    // head
    k_head1<<<GN, TB, 0, stream>>>(pooled, actions, fW1, fb1, z1);
    k_headbn<<<1, TB, 0, stream>>>(z1, g3, be3);
    k_head2<<<GN, 128, 0, stream>>>(z1, fW2, fb2, z2);
    k_head3<<<1, 64, 0, stream>>>(z2, fW3, fb3, out);
}

// Round 2
// 1080.886 us; speedup vs baseline: 1.2421x; 1.2421x over previous
//
#include <hip/hip_runtime.h>

#define NN 50000      // nodes
#define NE 800000     // edges
#define FD 128        // input feature dim
#define HD 256        // hidden dim
#define AD 32         // action dim
#define GN 50         // graphs
#define BN_EPS 1e-5f

// ---------------- degree / CSR build ----------------

__global__ void k_deg(const int* __restrict__ dst, int* __restrict__ counts) {
    int e = blockIdx.x * blockDim.x + threadIdx.x;
    if (e < NE) atomicAdd(&counts[dst[e]], 1);
}

__global__ void k_dis(const int* __restrict__ counts, float* __restrict__ dis) {
    int i = blockIdx.x * blockDim.x + threadIdx.x;
    if (i < NN) dis[i] = rsqrtf(1.0f + (float)counts[i]);
}

__global__ void k_scan1(const int* __restrict__ counts, int* __restrict__ rowptr,
                        int* __restrict__ bsum) {
    __shared__ int s[1024];
    int t = threadIdx.x;
    int i = blockIdx.x * 1024 + t;
    int v = (i < NN) ? counts[i] : 0;
    s[t] = v;
    __syncthreads();
    for (int off = 1; off < 1024; off <<= 1) {
        int u = (t >= off) ? s[t - off] : 0;
        __syncthreads();
        s[t] += u;
        __syncthreads();
    }
    if (i < NN) rowptr[i + 1] = s[t];
    if (t == 1023) bsum[blockIdx.x] = s[1023];
}

__global__ void k_scan2(int* __restrict__ bsum, int* __restrict__ rowptr, int nblk) {
    if (threadIdx.x == 0 && blockIdx.x == 0) {
        int run = 0;
        for (int b = 0; b < nblk; ++b) { int t = bsum[b]; bsum[b] = run; run += t; }
        rowptr[0] = 0;
    }
}

__global__ void k_scan3(int* __restrict__ rowptr, const int* __restrict__ bsum) {
    int i = blockIdx.x * blockDim.x + threadIdx.x;
    if (i < NN) rowptr[i + 1] += bsum[i >> 10];
}

__global__ void k_csr(const int* __restrict__ src, const int* __restrict__ dst,
                      const int* __restrict__ rowptr, int* __restrict__ fill,
                      const float* __restrict__ dis,
                      int* __restrict__ csr_src, float* __restrict__ csr_w) {
    int e = blockIdx.x * blockDim.x + threadIdx.x;
    if (e < NE) {
        int d = dst[e];
        int s = src[e];
        int p = rowptr[d] + atomicAdd(&fill[d], 1);
        csr_src[p] = s;
        csr_w[p] = dis[s] * dis[d];
    }
}

// ---------------- fp32 tiled GEMM: C[NN,HD] = A[NN,K] @ B[K,HD] ----------------

__global__ __launch_bounds__(256) void k_mm(const float* __restrict__ A,
                                            const float* __restrict__ B,
                                            float* __restrict__ C, int K) {
    __shared__ float As[16][68];   // transposed: As[k][row]
    __shared__ float Bs[16][68];
    int t = threadIdx.x;
    int tx = t & 15, ty = t >> 4;
    int rowBase = blockIdx.x * 64;
    int colBase = blockIdx.y * 64;
    float acc[4][4] = {};
    int ar  = t >> 2;          // 0..63 row within tile
    int akq = (t & 3) * 4;     // k offset 0,4,8,12
    int bkk = t >> 4;          // 0..15
    int bc  = (t & 15) * 4;    // 0..60

    for (int k0 = 0; k0 < K; k0 += 16) {
        int arow = rowBase + ar;
        float4 av = make_float4(0.f, 0.f, 0.f, 0.f);
        if (arow < NN) av = *(const float4*)&A[(size_t)arow * K + k0 + akq];
        As[akq + 0][ar] = av.x;
        As[akq + 1][ar] = av.y;
        As[akq + 2][ar] = av.z;
        As[akq + 3][ar] = av.w;
        float4 bv = *(const float4*)&B[(size_t)(k0 + bkk) * HD + colBase + bc];
        *(float4*)&Bs[bkk][bc] = bv;
        __syncthreads();
#pragma unroll
        for (int kk = 0; kk < 16; ++kk) {
            float4 a4 = *(const float4*)&As[kk][ty * 4];
            float4 b4 = *(const float4*)&Bs[kk][tx * 4];
            float a[4] = {a4.x, a4.y, a4.z, a4.w};
            float b[4] = {b4.x, b4.y, b4.z, b4.w};
#pragma unroll
            for (int i = 0; i < 4; ++i)
#pragma unroll
                for (int j = 0; j < 4; ++j)
                    acc[i][j] = fmaf(a[i], b[j], acc[i][j]);
        }
        __syncthreads();
    }
#pragma unroll
    for (int i = 0; i < 4; ++i) {
        int row = rowBase + ty * 4 + i;
        if (row < NN) {
            float4 v = make_float4(acc[i][0], acc[i][1], acc[i][2], acc[i][3]);
            *(float4*)&C[(size_t)row * HD + colBase + tx * 4] = v;
        }
    }
}

// ---------------- GCN aggregate + bias + relu ----------------

__global__ __launch_bounds__(256) void k_agg(const float* __restrict__ hw,
                                             const int* __restrict__ rowptr,
                                             const int* __restrict__ csr_src,
                                             const float* __restrict__ csr_w,
                                             const float* __restrict__ dis,
                                             const float* __restrict__ bias,
                                             float* __restrict__ out) {
    int n = blockIdx.x;
    int j = threadIdx.x;
    float d = dis[n];
    float acc = fmaf(hw[(size_t)n * HD + j], d * d, bias[j]);
    int e0 = rowptr[n], e1 = rowptr[n + 1];
    for (int e = e0; e < e1; ++e) {
        int s = csr_src[e];
        acc = fmaf(hw[(size_t)s * HD + j], csr_w[e], acc);
    }
    out[(size_t)n * HD + j] = fmaxf(acc, 0.0f);
}

// ---------------- batchnorm over NN rows ----------------

__global__ __launch_bounds__(256) void k_stats(const float* __restrict__ h,
                                               float* __restrict__ stats) {
    int j = threadIdx.x;
    int rows_per = (NN + gridDim.x - 1) / gridDim.x;
    int r0 = blockIdx.x * rows_per;
    int r1 = min(r0 + rows_per, NN);
    float s = 0.f, q = 0.f;
    for (int r = r0; r < r1; ++r) {
        float v = h[(size_t)r * HD + j];
        s += v;
        q = fmaf(v, v, q);
    }
    atomicAdd(&stats[j], s);
    atomicAdd(&stats[HD + j], q);
}

__global__ __launch_bounds__(256) void k_bn(float* __restrict__ h,
                                            const float* __restrict__ stats,
                                            const float* __restrict__ gamma,
                                            const float* __restrict__ beta) {
    size_t idx = (size_t)blockIdx.x * blockDim.x + threadIdx.x;
    if (idx < (size_t)NN * HD) {
        int j = idx & (HD - 1);
        float mu = stats[j] * (1.0f / NN);
        float var = stats[HD + j] * (1.0f / NN) - mu * mu;
        float rs = rsqrtf(var + BN_EPS);
        h[idx] = fmaf((h[idx] - mu) * rs, gamma[j], beta[j]);
    }
}

// ---------------- global mean pool (sorted batch -> segments) ----------------

// gstart[g] = first row index with batch >= g, for g in [0, GN]
__global__ void k_bounds(const int* __restrict__ batch, int* __restrict__ gstart) {
    int g = threadIdx.x;
    if (g <= GN) {
        int lo = 0, hi = NN;
        while (lo < hi) {
            int mid = (lo + hi) >> 1;
            if (batch[mid] < g) lo = mid + 1; else hi = mid;
        }
        gstart[g] = lo;
    }
}

// each block: 256 consecutive rows; thread j owns column j; register-accumulate
// per sorted segment, one atomicAdd per segment transition.
__global__ __launch_bounds__(256) void k_pool(const float* __restrict__ h,
                                              const int* __restrict__ batch,
                                              float* __restrict__ pooled) {
    int r0 = blockIdx.x * 256;
    int r1 = min(r0 + 256, NN);
    int j = threadIdx.x;
    float acc = 0.f;
    int curg = batch[r0];
    for (int r = r0; r < r1; ++r) {
        int g = batch[r];
        if (g != curg) {
            atomicAdd(&pooled[(size_t)curg * HD + j], acc);
            acc = 0.f;
            curg = g;
        }
        acc += h[(size_t)r * HD + j];
    }
    atomicAdd(&pooled[(size_t)curg * HD + j], acc);
}

__global__ void k_poolfin(float* __restrict__ pooled, const int* __restrict__ gstart) {
    int idx = blockIdx.x * blockDim.x + threadIdx.x;
    if (idx < GN * HD) {
        int g = idx >> 8;
        float c = (float)max(gstart[g + 1] - gstart[g], 1);
        pooled[idx] /= c;
    }
}

// ---------------- MLP head ----------------

__global__ __launch_bounds__(256) void k_head1(const float* __restrict__ pooled,
                                               const float* __restrict__ actions,
                                               const float* __restrict__ fW1,
                                               const float* __restrict__ fb1,
                                               float* __restrict__ z1) {
    int g = blockIdx.x, j = threadIdx.x;
    float acc = fb1[j];
    for (int k = 0; k < HD; ++k)
        acc = fmaf(pooled[g * HD + k], fW1[k * HD + j], acc);
    for (int k = 0; k < AD; ++k)
        acc = fmaf(actions[k], fW1[(HD + k) * HD + j], acc);
    z1[g * HD + j] = fmaxf(acc, 0.f);
}

__global__ __launch_bounds__(256) void k_headbn(float* __restrict__ z1,
                                                const float* __restrict__ g3,
                                                const float* __restrict__ be3) {
    int j = threadIdx.x;
    float s = 0.f, q = 0.f;
    for (int g = 0; g < GN; ++g) {
        float v = z1[g * HD + j];
        s += v;
        q = fmaf(v, v, q);
    }
    float mu = s * (1.0f / GN);
    float var = q * (1.0f / GN) - mu * mu;
    float rs = rsqrtf(var + BN_EPS);
    float ga = g3[j], be = be3[j];
    for (int g = 0; g < GN; ++g)
        z1[g * HD + j] = fmaf((z1[g * HD + j] - mu) * rs, ga, be);
}

__global__ __launch_bounds__(128) void k_head2(const float* __restrict__ z1,
                                               const float* __restrict__ fW2,
                                               const float* __restrict__ fb2,
                                               float* __restrict__ z2) {
    int g = blockIdx.x, j = threadIdx.x;
    float acc = fb2[j];
    for (int k = 0; k < HD; ++k)
        acc = fmaf(z1[g * HD + k], fW2[k * (HD / 2) + j], acc);
    z2[g * (HD / 2) + j] = fmaxf(acc, 0.f);
}

__global__ __launch_bounds__(64) void k_head3(const float* __restrict__ z2,
                                              const float* __restrict__ fW3,
                                              const float* __restrict__ fb3,
                                              float* __restrict__ out) {
    int g = threadIdx.x;
    if (g < GN) {
        float acc = fb3[0];
        for (int k = 0; k < HD / 2; ++k)
            acc = fmaf(z2[g * (HD / 2) + k], fW3[k], acc);
        out[g] = acc;
    }
}

// ---------------- launch ----------------

static inline size_t align256(size_t x) { return (x + 255) & ~(size_t)255; }

extern "C" void kernel_launch(void* const* d_in, const int* in_sizes, int n_in,
                              void* d_out, int out_size, void* d_ws, size_t ws_size,
                              hipStream_t stream) {
    const float* x       = (const float*)d_in[0];
    const int*   ei      = (const int*)d_in[1];
    const int*   batch   = (const int*)d_in[2];
    const float* actions = (const float*)d_in[3];
    const float* W1 = (const float*)d_in[4];
    const float* b1 = (const float*)d_in[5];
    const float* W2 = (const float*)d_in[6];
    const float* b2 = (const float*)d_in[7];
    const float* W3 = (const float*)d_in[8];
    const float* b3 = (const float*)d_in[9];
    const float* g1  = (const float*)d_in[10];
    const float* be1 = (const float*)d_in[11];
    const float* g2  = (const float*)d_in[12];
    const float* be2 = (const float*)d_in[13];
    const float* g3  = (const float*)d_in[14];
    const float* be3 = (const float*)d_in[15];
    const float* fW1 = (const float*)d_in[16];
    const float* fb1 = (const float*)d_in[17];
    const float* fW2 = (const float*)d_in[18];
    const float* fb2 = (const float*)d_in[19];
    const float* fW3 = (const float*)d_in[20];
    const float* fb3 = (const float*)d_in[21];
    float* out = (float*)d_out;

    const int* esrc = ei;
    const int* edst = ei + NE;

    // workspace carve
    char* p = (char*)d_ws;
    size_t off = 0;
    auto carve = [&](size_t bytes) { void* r = p + off; off = align256(off + bytes); return r; };
    float* hw      = (float*)carve((size_t)NN * HD * 4);
    float* cur     = (float*)carve((size_t)NN * HD * 4);
    float* dis     = (float*)carve((size_t)NN * 4);
    int*   counts  = (int*)carve((size_t)NN * 4);
    int*   rowptr  = (int*)carve((size_t)(NN + 1) * 4);
    int*   fill    = (int*)carve((size_t)NN * 4);
    int*   csr_src = (int*)carve((size_t)NE * 4);
    float* csr_w   = (float*)carve((size_t)NE * 4);
    int*   bsum    = (int*)carve(64 * 4);
    float* pooled  = (float*)carve((size_t)GN * HD * 4);
    int*   gstart  = (int*)carve((size_t)(GN + 1) * 4);
    float* stats   = (float*)carve(2 * HD * 4);
    float* z1      = (float*)carve((size_t)GN * HD * 4);
    float* z2      = (float*)carve((size_t)GN * (HD / 2) * 4);
    (void)ws_size;

    const int TB = 256;
    const int ebk = (NE + TB - 1) / TB;     // 3125
    const int nbk = (NN + TB - 1) / TB;     // 196
    const int scanblk = (NN + 1023) / 1024; // 49

    // degree + CSR
    hipMemsetAsync(counts, 0, (size_t)NN * 4, stream);
    k_deg<<<ebk, TB, 0, stream>>>(edst, counts);
    k_dis<<<nbk, TB, 0, stream>>>(counts, dis);
    k_scan1<<<scanblk, 1024, 0, stream>>>(counts, rowptr, bsum);
    k_scan2<<<1, 64, 0, stream>>>(bsum, rowptr, scanblk);
    k_scan3<<<nbk, TB, 0, stream>>>(rowptr, bsum);
    hipMemsetAsync(fill, 0, (size_t)NN * 4, stream);
    k_csr<<<ebk, TB, 0, stream>>>(esrc, edst, rowptr, fill, dis, csr_src, csr_w);

    dim3 mmgrid((NN + 63) / 64, HD / 64);

    // layer 1
    k_mm<<<mmgrid, TB, 0, stream>>>(x, W1, hw, FD);
    k_agg<<<NN, TB, 0, stream>>>(hw, rowptr, csr_src, csr_w, dis, b1, cur);
    hipMemsetAsync(stats, 0, 2 * HD * 4, stream);
    k_stats<<<256, TB, 0, stream>>>(cur, stats);
    k_bn<<<(NN * HD) / TB, TB, 0, stream>>>(cur, stats, g1, be1);

    // layer 2
    k_mm<<<mmgrid, TB, 0, stream>>>(cur, W2, hw, HD);
    k_agg<<<NN, TB, 0, stream>>>(hw, rowptr, csr_src, csr_w, dis, b2, cur);
    hipMemsetAsync(stats, 0, 2 * HD * 4, stream);
    k_stats<<<256, TB, 0, stream>>>(cur, stats);
    k_bn<<<(NN * HD) / TB, TB, 0, stream>>>(cur, stats, g2, be2);

    // layer 3 (relu only)
    k_mm<<<mmgrid, TB, 0, stream>>>(cur, W3, hw, HD);
    k_agg<<<NN, TB, 0, stream>>>(hw, rowptr, csr_src, csr_w, dis, b3, cur);

    // pool
    hipMemsetAsync(pooled, 0, (size_t)GN * HD * 4, stream);
    k_bounds<<<1, 64, 0, stream>>>(batch, gstart);
    k_pool<<<nbk, TB, 0, stream>>>(cur, batch, pooled);
    k_poolfin<<<(GN * HD + TB - 1) / TB, TB, 0, stream>>>(pooled, gstart);

    // head
    k_head1<<<GN, TB, 0, stream>>>(pooled, actions, fW1, fb1, z1);
    k_headbn<<<1, TB, 0, stream>>>(z1, g3, be3);
    k_head2<<<GN, 128, 0, stream>>>(z1, fW2, fb2, z2);
    k_head3<<<1, 64, 0, stream>>>(z2, fW3, fb3, out);
}

// Round 3
// 752.991 us; speedup vs baseline: 1.7830x; 1.4355x over previous
//
#include <hip/hip_runtime.h>

#define NN 50000      // nodes
#define NE 800000     // edges
#define FD 128        // input feature dim
#define HD 256        // hidden dim
#define AD 32         // action dim
#define GN 50         // graphs
#define BN_EPS 1e-5f

typedef float f32x4 __attribute__((ext_vector_type(4)));
typedef short s16x8 __attribute__((ext_vector_type(8)));

__device__ inline unsigned short f2bf(float f) {
    unsigned u = __float_as_uint(f);
    u += 0x7FFF + ((u >> 16) & 1);   // round-to-nearest-even
    return (unsigned short)(u >> 16);
}

// ---------------- degree / CSR build ----------------

__global__ void k_deg(const int* __restrict__ dst, int* __restrict__ counts) {
    int e = blockIdx.x * blockDim.x + threadIdx.x;
    if (e < NE) atomicAdd(&counts[dst[e]], 1);
}

__global__ void k_dis(const int* __restrict__ counts, float* __restrict__ dis) {
    int i = blockIdx.x * blockDim.x + threadIdx.x;
    if (i < NN) dis[i] = rsqrtf(1.0f + (float)counts[i]);
}

__global__ void k_scan1(const int* __restrict__ counts, int* __restrict__ rowptr,
                        int* __restrict__ bsum) {
    __shared__ int s[1024];
    int t = threadIdx.x;
    int i = blockIdx.x * 1024 + t;
    int v = (i < NN) ? counts[i] : 0;
    s[t] = v;
    __syncthreads();
    for (int off = 1; off < 1024; off <<= 1) {
        int u = (t >= off) ? s[t - off] : 0;
        __syncthreads();
        s[t] += u;
        __syncthreads();
    }
    if (i < NN) rowptr[i + 1] = s[t];
    if (t == 1023) bsum[blockIdx.x] = s[1023];
}

__global__ void k_scan2(int* __restrict__ bsum, int* __restrict__ rowptr, int nblk) {
    if (threadIdx.x == 0 && blockIdx.x == 0) {
        int run = 0;
        for (int b = 0; b < nblk; ++b) { int t = bsum[b]; bsum[b] = run; run += t; }
        rowptr[0] = 0;
    }
}

__global__ void k_scan3(int* __restrict__ rowptr, const int* __restrict__ bsum) {
    int i = blockIdx.x * blockDim.x + threadIdx.x;
    if (i < NN) rowptr[i + 1] += bsum[i >> 10];
}

__global__ void k_csr(const int* __restrict__ src, const int* __restrict__ dst,
                      const int* __restrict__ rowptr, int* __restrict__ fill,
                      const float* __restrict__ dis,
                      int* __restrict__ csr_src, float* __restrict__ csr_w) {
    int e = blockIdx.x * blockDim.x + threadIdx.x;
    if (e < NE) {
        int d = dst[e];
        int s = src[e];
        int p = rowptr[d] + atomicAdd(&fill[d], 1);
        csr_src[p] = s;
        csr_w[p] = dis[s] * dis[d];
    }
}

// ---------------- weight cast: W[K][HD] fp32 -> Wt[HD][K] bf16 ----------------

__global__ void k_castW(const float* __restrict__ W, unsigned short* __restrict__ Wt, int K) {
    int idx = blockIdx.x * 256 + threadIdx.x;
    if (idx < K * HD) {
        int c = idx / K, k = idx - c * K;
        Wt[idx] = f2bf(W[(size_t)k * HD + c]);
    }
}

// ---------------- MFMA bf16 GEMM: C[NN,HD] = A[NN,K] @ W[K,HD] ----------------
// A fp32 (converted to bf16 during LDS staging), Wt pre-cast bf16 [HD][K].
// Tile: 128 rows x 256 cols, 4 waves, each wave 32 rows x 256 cols.
// mfma_f32_16x16x32_bf16: A-frag lane l: row=l&15, k=(l>>4)*8+i (i=0..7)
//                         B-frag lane l: col=l&15, k=(l>>4)*8+i
//                         C/D  lane l, reg r: col=l&15, row=(l>>4)*4+r   [m89]

template<int K, bool BIASRELU>
__global__ __launch_bounds__(256) void k_mmf(const float* __restrict__ A,
                                             const unsigned short* __restrict__ Wt,
                                             const float* __restrict__ bias,
                                             float* __restrict__ C) {
    __shared__ __align__(16) short Als[128 * 40];   // [row][k] stride 40 shorts (80B)
    __shared__ __align__(16) short Bls[256 * 40];   // [col][k]
    int t = threadIdx.x;
    int rowBase = blockIdx.x * 128;
    int wid = t >> 6, lane = t & 63;
    int lr = lane & 15, kg = (lane >> 4) * 8;

    f32x4 acc[2][16];
#pragma unroll
    for (int i = 0; i < 2; ++i)
#pragma unroll
        for (int j = 0; j < 16; ++j) acc[i][j] = (f32x4){0.f, 0.f, 0.f, 0.f};

    for (int k0 = 0; k0 < K; k0 += 32) {
        // stage A: 128 rows x 32 k, fp32 -> bf16
#pragma unroll
        for (int it = 0; it < 2; ++it) {
            int task = t + it * 256;         // 0..511
            int row = task >> 2, kk = (task & 3) * 8;
            int grow = rowBase + row;
            float v[8];
            if (grow < NN) {
                f32x4 p0 = *(const f32x4*)&A[(size_t)grow * K + k0 + kk];
                f32x4 p1 = *(const f32x4*)&A[(size_t)grow * K + k0 + kk + 4];
                v[0] = p0.x; v[1] = p0.y; v[2] = p0.z; v[3] = p0.w;
                v[4] = p1.x; v[5] = p1.y; v[6] = p1.z; v[7] = p1.w;
            } else {
#pragma unroll
                for (int i = 0; i < 8; ++i) v[i] = 0.f;
            }
            union { s16x8 s; unsigned short u[8]; } pk;
#pragma unroll
            for (int i = 0; i < 8; ++i) pk.u[i] = f2bf(v[i]);
            *(s16x8*)&Als[row * 40 + kk] = pk.s;
        }
        // stage B: 256 cols x 32 k (bf16 already, contiguous in k)
#pragma unroll
        for (int it = 0; it < 4; ++it) {
            int task = t + it * 256;         // 0..1023
            int col = task >> 2, kk = (task & 3) * 8;
            *(s16x8*)&Bls[col * 40 + kk] = *(const s16x8*)&Wt[(size_t)col * K + k0 + kk];
        }
        __syncthreads();
        s16x8 a0 = *(const s16x8*)&Als[(wid * 32 + lr) * 40 + kg];
        s16x8 a1 = *(const s16x8*)&Als[(wid * 32 + 16 + lr) * 40 + kg];
#pragma unroll
        for (int nf = 0; nf < 16; ++nf) {
            s16x8 b = *(const s16x8*)&Bls[(nf * 16 + lr) * 40 + kg];
            acc[0][nf] = __builtin_amdgcn_mfma_f32_16x16x32_bf16(a0, b, acc[0][nf], 0, 0, 0);
            acc[1][nf] = __builtin_amdgcn_mfma_f32_16x16x32_bf16(a1, b, acc[1][nf], 0, 0, 0);
        }
        __syncthreads();
    }

    int r4 = (lane >> 4) * 4;
#pragma unroll
    for (int mf = 0; mf < 2; ++mf) {
#pragma unroll
        for (int r = 0; r < 4; ++r) {
            int row = rowBase + wid * 32 + mf * 16 + r4 + r;
            if (row < NN) {
#pragma unroll
                for (int nf = 0; nf < 16; ++nf) {
                    int col = nf * 16 + lr;
                    float vv = acc[mf][nf][r];
                    if (BIASRELU) vv = fmaxf(vv + bias[col], 0.f);
                    C[(size_t)row * HD + col] = vv;
                }
            }
        }
    }
}

// ---------------- GCN aggregate (gather, 8-way MLP unroll) ----------------
// out[n,j] = [bias+relu]( hw[n,j]*dis_n^2 + sum_e hw[src_e,j]*w_e )

template<int W, bool BIASRELU>
__global__ __launch_bounds__(256) void k_agg(const float* __restrict__ hw,
                                             const int* __restrict__ rowptr,
                                             const int* __restrict__ csr_src,
                                             const float* __restrict__ csr_w,
                                             const float* __restrict__ dis,
                                             const float* __restrict__ bias,
                                             float* __restrict__ out) {
    int n = (W == 256) ? (int)blockIdx.x : ((int)blockIdx.x * 2 + ((int)threadIdx.x >> 7));
    int j = threadIdx.x & (W - 1);
    if (n >= NN) return;
    float d = dis[n];
    float acc = hw[(size_t)n * W + j] * (d * d);
    int e0 = rowptr[n], e1 = rowptr[n + 1];
    int e = e0;
    for (; e + 8 <= e1; e += 8) {
        int s0 = csr_src[e+0], s1 = csr_src[e+1], s2 = csr_src[e+2], s3 = csr_src[e+3];
        int s4 = csr_src[e+4], s5 = csr_src[e+5], s6 = csr_src[e+6], s7 = csr_src[e+7];
        float w0 = csr_w[e+0], w1 = csr_w[e+1], w2 = csr_w[e+2], w3 = csr_w[e+3];
        float w4 = csr_w[e+4], w5 = csr_w[e+5], w6 = csr_w[e+6], w7 = csr_w[e+7];
        float v0 = hw[(size_t)s0 * W + j], v1 = hw[(size_t)s1 * W + j];
        float v2 = hw[(size_t)s2 * W + j], v3 = hw[(size_t)s3 * W + j];
        float v4 = hw[(size_t)s4 * W + j], v5 = hw[(size_t)s5 * W + j];
        float v6 = hw[(size_t)s6 * W + j], v7 = hw[(size_t)s7 * W + j];
        acc = fmaf(v0, w0, acc); acc = fmaf(v1, w1, acc);
        acc = fmaf(v2, w2, acc); acc = fmaf(v3, w3, acc);
        acc = fmaf(v4, w4, acc); acc = fmaf(v5, w5, acc);
        acc = fmaf(v6, w6, acc); acc = fmaf(v7, w7, acc);
    }
    for (; e < e1; ++e)
        acc = fmaf(hw[(size_t)csr_src[e] * W + j], csr_w[e], acc);
    if (BIASRELU) acc = fmaxf(acc + bias[j], 0.f);
    out[(size_t)n * W + j] = acc;
}

// ---------------- batchnorm over NN rows ----------------

__global__ __launch_bounds__(256) void k_stats(const float* __restrict__ h,
                                               float* __restrict__ stats) {
    int j = threadIdx.x;
    int rows_per = (NN + gridDim.x - 1) / gridDim.x;
    int r0 = blockIdx.x * rows_per;
    int r1 = min(r0 + rows_per, NN);
    float s = 0.f, q = 0.f;
    for (int r = r0; r < r1; ++r) {
        float v = h[(size_t)r * HD + j];
        s += v;
        q = fmaf(v, v, q);
    }
    atomicAdd(&stats[j], s);
    atomicAdd(&stats[HD + j], q);
}

__global__ __launch_bounds__(256) void k_bn(float* __restrict__ h,
                                            const float* __restrict__ stats,
                                            const float* __restrict__ gamma,
                                            const float* __restrict__ beta) {
    size_t idx = (size_t)blockIdx.x * blockDim.x + threadIdx.x;
    if (idx < (size_t)NN * HD) {
        int j = idx & (HD - 1);
        float mu = stats[j] * (1.0f / NN);
        float var = stats[HD + j] * (1.0f / NN) - mu * mu;
        float rs = rsqrtf(var + BN_EPS);
        h[idx] = fmaf((h[idx] - mu) * rs, gamma[j], beta[j]);
    }
}

// ---------------- global mean pool (sorted batch -> segments) ----------------

__global__ void k_bounds(const int* __restrict__ batch, int* __restrict__ gstart) {
    int g = threadIdx.x;
    if (g <= GN) {
        int lo = 0, hi = NN;
        while (lo < hi) {
            int mid = (lo + hi) >> 1;
            if (batch[mid] < g) lo = mid + 1; else hi = mid;
        }
        gstart[g] = lo;
    }
}

__global__ __launch_bounds__(256) void k_pool(const float* __restrict__ h,
                                              const int* __restrict__ batch,
                                              float* __restrict__ pooled) {
    int r0 = blockIdx.x * 256;
    int r1 = min(r0 + 256, NN);
    int j = threadIdx.x;
    float acc = 0.f;
    int curg = batch[r0];
    for (int r = r0; r < r1; ++r) {
        int g = batch[r];
        if (g != curg) {
            atomicAdd(&pooled[(size_t)curg * HD + j], acc);
            acc = 0.f;
            curg = g;
        }
        acc += h[(size_t)r * HD + j];
    }
    atomicAdd(&pooled[(size_t)curg * HD + j], acc);
}

__global__ void k_poolfin(float* __restrict__ pooled, const int* __restrict__ gstart) {
    int idx = blockIdx.x * blockDim.x + threadIdx.x;
    if (idx < GN * HD) {
        int g = idx >> 8;
        float c = (float)max(gstart[g + 1] - gstart[g], 1);
        pooled[idx] /= c;
    }
}

// ---------------- MLP head ----------------

__global__ __launch_bounds__(256) void k_head1(const float* __restrict__ pooled,
                                               const float* __restrict__ actions,
                                               const float* __restrict__ fW1,
                                               const float* __restrict__ fb1,
                                               float* __restrict__ z1) {
    int g = blockIdx.x, j = threadIdx.x;
    float acc = fb1[j];
    for (int k = 0; k < HD; ++k)
        acc = fmaf(pooled[g * HD + k], fW1[k * HD + j], acc);
    for (int k = 0; k < AD; ++k)
        acc = fmaf(actions[k], fW1[(HD + k) * HD + j], acc);
    z1[g * HD + j] = fmaxf(acc, 0.f);
}

__global__ __launch_bounds__(256) void k_headbn(float* __restrict__ z1,
                                                const float* __restrict__ g3,
                                                const float* __restrict__ be3) {
    int j = threadIdx.x;
    float s = 0.f, q = 0.f;
    for (int g = 0; g < GN; ++g) {
        float v = z1[g * HD + j];
        s += v;
        q = fmaf(v, v, q);
    }
    float mu = s * (1.0f / GN);
    float var = q * (1.0f / GN) - mu * mu;
    float rs = rsqrtf(var + BN_EPS);
    float ga = g3[j], be = be3[j];
    for (int g = 0; g < GN; ++g)
        z1[g * HD + j] = fmaf((z1[g * HD + j] - mu) * rs, ga, be);
}

__global__ __launch_bounds__(128) void k_head2(const float* __restrict__ z1,
                                               const float* __restrict__ fW2,
                                               const float* __restrict__ fb2,
                                               float* __restrict__ z2) {
    int g = blockIdx.x, j = threadIdx.x;
    float acc = fb2[j];
    for (int k = 0; k < HD; ++k)
        acc = fmaf(z1[g * HD + k], fW2[k * (HD / 2) + j], acc);
    z2[g * (HD / 2) + j] = fmaxf(acc, 0.f);
}

__global__ __launch_bounds__(64) void k_head3(const float* __restrict__ z2,
                                              const float* __restrict__ fW3,
                                              const float* __restrict__ fb3,
                                              float* __restrict__ out) {
    int g = threadIdx.x;
    if (g < GN) {
        float acc = fb3[0];
        for (int k = 0; k < HD / 2; ++k)
            acc = fmaf(z2[g * (HD / 2) + k], fW3[k], acc);
        out[g] = acc;
    }
}

// ---------------- launch ----------------

static inline size_t align256(size_t x) { return (x + 255) & ~(size_t)255; }

extern "C" void kernel_launch(void* const* d_in, const int* in_sizes, int n_in,
                              void* d_out, int out_size, void* d_ws, size_t ws_size,
                              hipStream_t stream) {
    const float* x       = (const float*)d_in[0];
    const int*   ei      = (const int*)d_in[1];
    const int*   batch   = (const int*)d_in[2];
    const float* actions = (const float*)d_in[3];
    const float* W1 = (const float*)d_in[4];
    const float* b1 = (const float*)d_in[5];
    const float* W2 = (const float*)d_in[6];
    const float* b2 = (const float*)d_in[7];
    const float* W3 = (const float*)d_in[8];
    const float* b3 = (const float*)d_in[9];
    const float* g1  = (const float*)d_in[10];
    const float* be1 = (const float*)d_in[11];
    const float* g2  = (const float*)d_in[12];
    const float* be2 = (const float*)d_in[13];
    const float* g3  = (const float*)d_in[14];
    const float* be3 = (const float*)d_in[15];
    const float* fW1 = (const float*)d_in[16];
    const float* fb1 = (const float*)d_in[17];
    const float* fW2 = (const float*)d_in[18];
    const float* fb2 = (const float*)d_in[19];
    const float* fW3 = (const float*)d_in[20];
    const float* fb3 = (const float*)d_in[21];
    float* out = (float*)d_out;

    const int* esrc = ei;
    const int* edst = ei + NE;

    // workspace carve
    char* p = (char*)d_ws;
    size_t off = 0;
    auto carve = [&](size_t bytes) { void* r = p + off; off = align256(off + bytes); return r; };
    float* hw      = (float*)carve((size_t)NN * HD * 4);
    float* cur     = (float*)carve((size_t)NN * HD * 4);
    float* xa      = (float*)carve((size_t)NN * FD * 4);
    float* dis     = (float*)carve((size_t)NN * 4);
    int*   counts  = (int*)carve((size_t)NN * 4);
    int*   rowptr  = (int*)carve((size_t)(NN + 1) * 4);
    int*   fill    = (int*)carve((size_t)NN * 4);
    int*   csr_src = (int*)carve((size_t)NE * 4);
    float* csr_w   = (float*)carve((size_t)NE * 4);
    int*   bsum    = (int*)carve(64 * 4);
    float* pooled  = (float*)carve((size_t)GN * HD * 4);
    int*   gstart  = (int*)carve((size_t)(GN + 1) * 4);
    float* stats   = (float*)carve(2 * HD * 4);
    float* z1      = (float*)carve((size_t)GN * HD * 4);
    float* z2      = (float*)carve((size_t)GN * (HD / 2) * 4);
    unsigned short* W1t = (unsigned short*)carve((size_t)FD * HD * 2);
    unsigned short* W2t = (unsigned short*)carve((size_t)HD * HD * 2);
    unsigned short* W3t = (unsigned short*)carve((size_t)HD * HD * 2);
    (void)ws_size;

    const int TB = 256;
    const int ebk = (NE + TB - 1) / TB;
    const int nbk = (NN + TB - 1) / TB;
    const int scanblk = (NN + 1023) / 1024;
    const int mmg = (NN + 127) / 128;       // 391

    // weight casts (independent of graph)
    k_castW<<<(FD * HD + 255) / 256, 256, 0, stream>>>(W1, W1t, FD);
    k_castW<<<(HD * HD + 255) / 256, 256, 0, stream>>>(W2, W2t, HD);
    k_castW<<<(HD * HD + 255) / 256, 256, 0, stream>>>(W3, W3t, HD);

    // degree + CSR
    hipMemsetAsync(counts, 0, (size_t)NN * 4, stream);
    k_deg<<<ebk, TB, 0, stream>>>(edst, counts);
    k_dis<<<nbk, TB, 0, stream>>>(counts, dis);
    k_scan1<<<scanblk, 1024, 0, stream>>>(counts, rowptr, bsum);
    k_scan2<<<1, 64, 0, stream>>>(bsum, rowptr, scanblk);
    k_scan3<<<nbk, TB, 0, stream>>>(rowptr, bsum);
    hipMemsetAsync(fill, 0, (size_t)NN * 4, stream);
    k_csr<<<ebk, TB, 0, stream>>>(esrc, edst, rowptr, fill, dis, csr_src, csr_w);

    // layer 1: aggregate-first (linearity), then GEMM with bias+relu epilogue
    k_agg<FD, false><<<NN / 2, TB, 0, stream>>>(x, rowptr, csr_src, csr_w, dis, nullptr, xa);
    k_mmf<FD, true><<<mmg, TB, 0, stream>>>(xa, W1t, b1, cur);
    hipMemsetAsync(stats, 0, 2 * HD * 4, stream);
    k_stats<<<256, TB, 0, stream>>>(cur, stats);
    k_bn<<<(NN * HD) / TB, TB, 0, stream>>>(cur, stats, g1, be1);

    // layer 2
    k_mmf<HD, false><<<mmg, TB, 0, stream>>>(cur, W2t, nullptr, hw);
    k_agg<HD, true><<<NN, TB, 0, stream>>>(hw, rowptr, csr_src, csr_w, dis, b2, cur);
    hipMemsetAsync(stats, 0, 2 * HD * 4, stream);
    k_stats<<<256, TB, 0, stream>>>(cur, stats);
    k_bn<<<(NN * HD) / TB, TB, 0, stream>>>(cur, stats, g2, be2);

    // layer 3 (relu only)
    k_mmf<HD, false><<<mmg, TB, 0, stream>>>(cur, W3t, nullptr, hw);
    k_agg<HD, true><<<NN, TB, 0, stream>>>(hw, rowptr, csr_src, csr_w, dis, b3, cur);

    // pool
    hipMemsetAsync(pooled, 0, (size_t)GN * HD * 4, stream);
    k_bounds<<<1, 64, 0, stream>>>(batch, gstart);
    k_pool<<<nbk, TB, 0, stream>>>(cur, batch, pooled);
    k_poolfin<<<(GN * HD + TB - 1) / TB, TB, 0, stream>>>(pooled, gstart);

    // head
    k_head1<<<GN, TB, 0, stream>>>(pooled, actions, fW1, fb1, z1);
    k_headbn<<<1, TB, 0, stream>>>(z1, g3, be3);
    k_head2<<<GN, 128, 0, stream>>>(z1, fW2, fb2, z2);
    k_head3<<<1, 64, 0, stream>>>(z2, fW3, fb3, out);
}

// Round 4
// 620.964 us; speedup vs baseline: 2.1621x; 1.2126x over previous
//
#include <hip/hip_runtime.h>

#define NN 50000      // nodes
#define NE 800000     // edges
#define FD 128        // input feature dim
#define HD 256        // hidden dim
#define AD 32         // action dim
#define GN 50         // graphs
#define BN_EPS 1e-5f

typedef float f32x4 __attribute__((ext_vector_type(4)));
typedef short s16x8 __attribute__((ext_vector_type(8)));

__device__ inline unsigned short f2bf(float f) {
    unsigned u = __float_as_uint(f);
    u += 0x7FFF + ((u >> 16) & 1);   // round-to-nearest-even
    return (unsigned short)(u >> 16);
}
__device__ inline float bflo(unsigned u) { return __uint_as_float(u << 16); }
__device__ inline float bfhi(unsigned u) { return __uint_as_float(u & 0xffff0000u); }

// ---------------- degree / CSR build ----------------

__global__ void k_deg(const int* __restrict__ dst, int* __restrict__ counts) {
    int e = blockIdx.x * blockDim.x + threadIdx.x;
    if (e < NE) atomicAdd(&counts[dst[e]], 1);
}

__global__ void k_dis(const int* __restrict__ counts, float* __restrict__ dis) {
    int i = blockIdx.x * blockDim.x + threadIdx.x;
    if (i < NN) dis[i] = rsqrtf(1.0f + (float)counts[i]);
}

__global__ void k_scan1(const int* __restrict__ counts, int* __restrict__ rowptr,
                        int* __restrict__ bsum) {
    __shared__ int s[1024];
    int t = threadIdx.x;
    int i = blockIdx.x * 1024 + t;
    int v = (i < NN) ? counts[i] : 0;
    s[t] = v;
    __syncthreads();
    for (int off = 1; off < 1024; off <<= 1) {
        int u = (t >= off) ? s[t - off] : 0;
        __syncthreads();
        s[t] += u;
        __syncthreads();
    }
    if (i < NN) rowptr[i + 1] = s[t];
    if (t == 1023) bsum[blockIdx.x] = s[1023];
}

__global__ void k_scan2(int* __restrict__ bsum, int* __restrict__ rowptr, int nblk) {
    if (threadIdx.x == 0 && blockIdx.x == 0) {
        int run = 0;
        for (int b = 0; b < nblk; ++b) { int t = bsum[b]; bsum[b] = run; run += t; }
        rowptr[0] = 0;
    }
}

__global__ void k_scan3(int* __restrict__ rowptr, const int* __restrict__ bsum) {
    int i = blockIdx.x * blockDim.x + threadIdx.x;
    if (i < NN) rowptr[i + 1] += bsum[i >> 10];
}

__global__ void k_csr(const int* __restrict__ src, const int* __restrict__ dst,
                      const int* __restrict__ rowptr, int* __restrict__ fill,
                      const float* __restrict__ dis,
                      int* __restrict__ csr_src, float* __restrict__ csr_w) {
    int e = blockIdx.x * blockDim.x + threadIdx.x;
    if (e < NE) {
        int d = dst[e];
        int s = src[e];
        int p = rowptr[d] + atomicAdd(&fill[d], 1);
        csr_src[p] = s;
        csr_w[p] = dis[s] * dis[d];
    }
}

// wsum[n] = 1/deg_n + sum_e w_e  (agg of ones-vector; used for BN affine fold)
__global__ void k_wsum(const int* __restrict__ rowptr, const float* __restrict__ csr_w,
                       const float* __restrict__ dis, float* __restrict__ wsum) {
    int n = blockIdx.x * 256 + threadIdx.x;
    if (n < NN) {
        float d = dis[n];
        float s = d * d;
        int e1 = rowptr[n + 1];
        for (int e = rowptr[n]; e < e1; ++e) s += csr_w[e];
        wsum[n] = s;
    }
}

// ---------------- casts ----------------

__global__ void k_castW(const float* __restrict__ W, unsigned short* __restrict__ Wt, int K) {
    int idx = blockIdx.x * 256 + threadIdx.x;
    if (idx < K * HD) {
        int c = idx / K, k = idx - c * K;
        Wt[idx] = f2bf(W[(size_t)k * HD + c]);
    }
}

__global__ void k_castx(const float* __restrict__ x, unsigned* __restrict__ xb) {
    int idx = blockIdx.x * 256 + threadIdx.x;
    if (idx < NN * (FD / 2)) {
        float2 v = *(const float2*)&x[(size_t)idx * 2];
        xb[idx] = ((unsigned)f2bf(v.y) << 16) | f2bf(v.x);
    }
}

// ---------------- MFMA bf16 GEMM: C[NN,HD] = A[NN,K] @ W[K,HD], bias+relu ----------------
// A bf16-packed [NN, K/2] uints; Wt bf16 [HD][K].
// Tile 128x256, 4 waves. mfma_f32_16x16x32_bf16, C/D: col=lane&15, row=(lane>>4)*4+reg.

template<int K, bool BF16OUT>
__global__ __launch_bounds__(256) void k_mmf(const unsigned* __restrict__ Ab,
                                             const unsigned short* __restrict__ Wt,
                                             const float* __restrict__ bias,
                                             void* __restrict__ Cout) {
    __shared__ __align__(16) short Als[128 * 40];   // [row][k] stride 40 shorts
    __shared__ __align__(16) short Bls[256 * 40];   // [col][k]
    constexpr int UK = K / 2;                        // uints per A row
    int t = threadIdx.x;
    int rowBase = blockIdx.x * 128;
    int wid = t >> 6, lane = t & 63;
    int lr = lane & 15, kg = (lane >> 4) * 8;

    f32x4 acc[2][16];
#pragma unroll
    for (int i = 0; i < 2; ++i)
#pragma unroll
        for (int j = 0; j < 16; ++j) acc[i][j] = (f32x4){0.f, 0.f, 0.f, 0.f};

    for (int k0 = 0; k0 < K; k0 += 32) {
        // stage A: 128 rows x 32 k bf16 (copy, no conversion)
#pragma unroll
        for (int it = 0; it < 2; ++it) {
            int task = t + it * 256;          // 0..511
            int row = task >> 2, k8 = (task & 3) * 8;
            int grow = rowBase + row;
            s16x8 v = (s16x8)(short)0;
            if (grow < NN)
                v = *(const s16x8*)&Ab[(size_t)grow * UK + (k0 >> 1) + (task & 3) * 4];
            *(s16x8*)&Als[row * 40 + k8] = v;
        }
        // stage B: 256 cols x 32 k
#pragma unroll
        for (int it = 0; it < 4; ++it) {
            int task = t + it * 256;          // 0..1023
            int col = task >> 2, k8 = (task & 3) * 8;
            *(s16x8*)&Bls[col * 40 + k8] = *(const s16x8*)&Wt[(size_t)col * K + k0 + k8];
        }
        __syncthreads();
        s16x8 a0 = *(const s16x8*)&Als[(wid * 32 + lr) * 40 + kg];
        s16x8 a1 = *(const s16x8*)&Als[(wid * 32 + 16 + lr) * 40 + kg];
#pragma unroll
        for (int nf = 0; nf < 16; ++nf) {
            s16x8 b = *(const s16x8*)&Bls[(nf * 16 + lr) * 40 + kg];
            acc[0][nf] = __builtin_amdgcn_mfma_f32_16x16x32_bf16(a0, b, acc[0][nf], 0, 0, 0);
            acc[1][nf] = __builtin_amdgcn_mfma_f32_16x16x32_bf16(a1, b, acc[1][nf], 0, 0, 0);
        }
        __syncthreads();
    }

    int r4 = (lane >> 4) * 4;
#pragma unroll
    for (int mf = 0; mf < 2; ++mf) {
#pragma unroll
        for (int r = 0; r < 4; ++r) {
            int row = rowBase + wid * 32 + mf * 16 + r4 + r;
            if (row < NN) {
#pragma unroll
                for (int nf = 0; nf < 16; ++nf) {
                    int col = nf * 16 + lr;
                    float vv = fmaxf(acc[mf][nf][r] + bias[col], 0.f);
                    if (BF16OUT)
                        ((unsigned short*)Cout)[(size_t)row * HD + col] = f2bf(vv);
                    else
                        ((float*)Cout)[(size_t)row * HD + col] = vv;
                }
            }
        }
    }
}

// ---------------- GCN aggregate on bf16-packed tensor, optional BN-affine fold ----------------
// AFFINE: out = a_j * agg(t)[n,j] + c_j * wsum_n   (h = a*t+c folded through linear agg)

template<int W, bool AFFINE>
__global__ __launch_bounds__(256) void k_aggb(const unsigned* __restrict__ tin,
                                              const int* __restrict__ rowptr,
                                              const int* __restrict__ csr_src,
                                              const float* __restrict__ csr_w,
                                              const float* __restrict__ dis,
                                              const float* __restrict__ aff_a,
                                              const float* __restrict__ aff_c,
                                              const float* __restrict__ wsum,
                                              unsigned* __restrict__ outp) {
    constexpr int U = W / 2;          // uints per row
    constexpr int NPB = 256 / U;      // nodes per block (HD:2, FD:4)
    int jj = threadIdx.x & (U - 1);
    int local = threadIdx.x / U;
    int n = blockIdx.x * NPB + local;
    if (n >= NN) return;
    float d = dis[n];
    float self = d * d;
    unsigned u0 = tin[(size_t)n * U + jj];
    float acc0 = bflo(u0) * self;
    float acc1 = bfhi(u0) * self;
    int e0 = rowptr[n], e1 = rowptr[n + 1];
    int e = e0;
    for (; e + 8 <= e1; e += 8) {
        int s0 = csr_src[e+0], s1 = csr_src[e+1], s2 = csr_src[e+2], s3 = csr_src[e+3];
        int s4 = csr_src[e+4], s5 = csr_src[e+5], s6 = csr_src[e+6], s7 = csr_src[e+7];
        float w0 = csr_w[e+0], w1 = csr_w[e+1], w2 = csr_w[e+2], w3 = csr_w[e+3];
        float w4 = csr_w[e+4], w5 = csr_w[e+5], w6 = csr_w[e+6], w7 = csr_w[e+7];
        unsigned v0 = tin[(size_t)s0 * U + jj], v1 = tin[(size_t)s1 * U + jj];
        unsigned v2 = tin[(size_t)s2 * U + jj], v3 = tin[(size_t)s3 * U + jj];
        unsigned v4 = tin[(size_t)s4 * U + jj], v5 = tin[(size_t)s5 * U + jj];
        unsigned v6 = tin[(size_t)s6 * U + jj], v7 = tin[(size_t)s7 * U + jj];
        acc0 = fmaf(bflo(v0), w0, acc0); acc1 = fmaf(bfhi(v0), w0, acc1);
        acc0 = fmaf(bflo(v1), w1, acc0); acc1 = fmaf(bfhi(v1), w1, acc1);
        acc0 = fmaf(bflo(v2), w2, acc0); acc1 = fmaf(bfhi(v2), w2, acc1);
        acc0 = fmaf(bflo(v3), w3, acc0); acc1 = fmaf(bfhi(v3), w3, acc1);
        acc0 = fmaf(bflo(v4), w4, acc0); acc1 = fmaf(bfhi(v4), w4, acc1);
        acc0 = fmaf(bflo(v5), w5, acc0); acc1 = fmaf(bfhi(v5), w5, acc1);
        acc0 = fmaf(bflo(v6), w6, acc0); acc1 = fmaf(bfhi(v6), w6, acc1);
        acc0 = fmaf(bflo(v7), w7, acc0); acc1 = fmaf(bfhi(v7), w7, acc1);
    }
    for (; e < e1; ++e) {
        unsigned v = tin[(size_t)csr_src[e] * U + jj];
        float w = csr_w[e];
        acc0 = fmaf(bflo(v), w, acc0);
        acc1 = fmaf(bfhi(v), w, acc1);
    }
    if (AFFINE) {
        float wn = wsum[n];
        float2 a2 = *(const float2*)&aff_a[2 * jj];
        float2 c2 = *(const float2*)&aff_c[2 * jj];
        acc0 = fmaf(a2.x, acc0, c2.x * wn);
        acc1 = fmaf(a2.y, acc1, c2.y * wn);
    }
    outp[(size_t)n * U + jj] = ((unsigned)f2bf(acc1) << 16) | f2bf(acc0);
}

// ---------------- batchnorm stats on bf16-packed tensor + affine precompute ----------------

__global__ __launch_bounds__(256) void k_statsb(const unsigned* __restrict__ t,
                                                float* __restrict__ stats) {
    int jj = threadIdx.x & 127, half = threadIdx.x >> 7;
    int rows_per = (NN + gridDim.x - 1) / gridDim.x;
    int r0 = blockIdx.x * rows_per;
    int r1 = min(r0 + rows_per, NN);
    float s0 = 0.f, q0 = 0.f, s1 = 0.f, q1 = 0.f;
    for (int r = r0 + half; r < r1; r += 2) {
        unsigned u = t[(size_t)r * 128 + jj];
        float v0 = bflo(u), v1 = bfhi(u);
        s0 += v0; q0 = fmaf(v0, v0, q0);
        s1 += v1; q1 = fmaf(v1, v1, q1);
    }
    atomicAdd(&stats[2 * jj], s0);
    atomicAdd(&stats[2 * jj + 1], s1);
    atomicAdd(&stats[HD + 2 * jj], q0);
    atomicAdd(&stats[HD + 2 * jj + 1], q1);
}

__global__ void k_affine(const float* __restrict__ stats, const float* __restrict__ g,
                         const float* __restrict__ be, float* __restrict__ a,
                         float* __restrict__ c) {
    int j = threadIdx.x;
    float mu = stats[j] * (1.0f / NN);
    float var = stats[HD + j] * (1.0f / NN) - mu * mu;
    float rs = rsqrtf(var + BN_EPS);
    float aj = g[j] * rs;
    a[j] = aj;
    c[j] = be[j] - mu * aj;
}

// ---------------- global mean pool (sorted batch -> segments) ----------------

__global__ void k_bounds(const int* __restrict__ batch, int* __restrict__ gstart) {
    int g = threadIdx.x;
    if (g <= GN) {
        int lo = 0, hi = NN;
        while (lo < hi) {
            int mid = (lo + hi) >> 1;
            if (batch[mid] < g) lo = mid + 1; else hi = mid;
        }
        gstart[g] = lo;
    }
}

__global__ __launch_bounds__(256) void k_pool(const float* __restrict__ h,
                                              const int* __restrict__ batch,
                                              float* __restrict__ pooled) {
    int r0 = blockIdx.x * 256;
    int r1 = min(r0 + 256, NN);
    int j = threadIdx.x;
    float acc = 0.f;
    int curg = batch[r0];
    for (int r = r0; r < r1; ++r) {
        int g = batch[r];
        if (g != curg) {
            atomicAdd(&pooled[(size_t)curg * HD + j], acc);
            acc = 0.f;
            curg = g;
        }
        acc += h[(size_t)r * HD + j];
    }
    atomicAdd(&pooled[(size_t)curg * HD + j], acc);
}

__global__ void k_poolfin(float* __restrict__ pooled, const int* __restrict__ gstart) {
    int idx = blockIdx.x * blockDim.x + threadIdx.x;
    if (idx < GN * HD) {
        int g = idx >> 8;
        float c = (float)max(gstart[g + 1] - gstart[g], 1);
        pooled[idx] /= c;
    }
}

// ---------------- MLP head ----------------

__global__ __launch_bounds__(256) void k_head1(const float* __restrict__ pooled,
                                               const float* __restrict__ actions,
                                               const float* __restrict__ fW1,
                                               const float* __restrict__ fb1,
                                               float* __restrict__ z1) {
    int g = blockIdx.x, j = threadIdx.x;
    float acc = fb1[j];
    for (int k = 0; k < HD; ++k)
        acc = fmaf(pooled[g * HD + k], fW1[k * HD + j], acc);
    for (int k = 0; k < AD; ++k)
        acc = fmaf(actions[k], fW1[(HD + k) * HD + j], acc);
    z1[g * HD + j] = fmaxf(acc, 0.f);
}

__global__ __launch_bounds__(256) void k_headbn(float* __restrict__ z1,
                                                const float* __restrict__ g3,
                                                const float* __restrict__ be3) {
    int j = threadIdx.x;
    float s = 0.f, q = 0.f;
    for (int g = 0; g < GN; ++g) {
        float v = z1[g * HD + j];
        s += v;
        q = fmaf(v, v, q);
    }
    float mu = s * (1.0f / GN);
    float var = q * (1.0f / GN) - mu * mu;
    float rs = rsqrtf(var + BN_EPS);
    float ga = g3[j], be = be3[j];
    for (int g = 0; g < GN; ++g)
        z1[g * HD + j] = fmaf((z1[g * HD + j] - mu) * rs, ga, be);
}

__global__ __launch_bounds__(128) void k_head2(const float* __restrict__ z1,
                                               const float* __restrict__ fW2,
                                               const float* __restrict__ fb2,
                                               float* __restrict__ z2) {
    int g = blockIdx.x, j = threadIdx.x;
    float acc = fb2[j];
    for (int k = 0; k < HD; ++k)
        acc = fmaf(z1[g * HD + k], fW2[k * (HD / 2) + j], acc);
    z2[g * (HD / 2) + j] = fmaxf(acc, 0.f);
}

__global__ __launch_bounds__(64) void k_head3(const float* __restrict__ z2,
                                              const float* __restrict__ fW3,
                                              const float* __restrict__ fb3,
                                              float* __restrict__ out) {
    int g = threadIdx.x;
    if (g < GN) {
        float acc = fb3[0];
        for (int k = 0; k < HD / 2; ++k)
            acc = fmaf(z2[g * (HD / 2) + k], fW3[k], acc);
        out[g] = acc;
    }
}

// ---------------- launch ----------------

static inline size_t align256(size_t x) { return (x + 255) & ~(size_t)255; }

extern "C" void kernel_launch(void* const* d_in, const int* in_sizes, int n_in,
                              void* d_out, int out_size, void* d_ws, size_t ws_size,
                              hipStream_t stream) {
    const float* x       = (const float*)d_in[0];
    const int*   ei      = (const int*)d_in[1];
    const int*   batch   = (const int*)d_in[2];
    const float* actions = (const float*)d_in[3];
    const float* W1 = (const float*)d_in[4];
    const float* b1 = (const float*)d_in[5];
    const float* W2 = (const float*)d_in[6];
    const float* b2 = (const float*)d_in[7];
    const float* W3 = (const float*)d_in[8];
    const float* b3 = (const float*)d_in[9];
    const float* g1  = (const float*)d_in[10];
    const float* be1 = (const float*)d_in[11];
    const float* g2  = (const float*)d_in[12];
    const float* be2 = (const float*)d_in[13];
    const float* g3  = (const float*)d_in[14];
    const float* be3 = (const float*)d_in[15];
    const float* fW1 = (const float*)d_in[16];
    const float* fb1 = (const float*)d_in[17];
    const float* fW2 = (const float*)d_in[18];
    const float* fb2 = (const float*)d_in[19];
    const float* fW3 = (const float*)d_in[20];
    const float* fb3 = (const float*)d_in[21];
    float* out = (float*)d_out;

    const int* esrc = ei;
    const int* edst = ei + NE;

    // workspace carve
    char* p = (char*)d_ws;
    size_t off = 0;
    auto carve = [&](size_t bytes) { void* r = p + off; off = align256(off + bytes); return r; };
    unsigned* xb   = (unsigned*)carve((size_t)NN * (FD / 2) * 4);   // x in bf16
    unsigned* xa   = (unsigned*)carve((size_t)NN * (FD / 2) * 4);   // agg(x)
    unsigned* tbuf = (unsigned*)carve((size_t)NN * (HD / 2) * 4);   // t1 / t2 (bf16)
    unsigned* ah   = (unsigned*)carve((size_t)NN * (HD / 2) * 4);   // agg+BN output
    float* cur     = (float*)carve((size_t)NN * HD * 4);            // t3 fp32
    float* dis     = (float*)carve((size_t)NN * 4);
    int*   counts  = (int*)carve((size_t)NN * 4);
    int*   rowptr  = (int*)carve((size_t)(NN + 1) * 4);
    int*   fill    = (int*)carve((size_t)NN * 4);
    int*   csr_src = (int*)carve((size_t)NE * 4);
    float* csr_w   = (float*)carve((size_t)NE * 4);
    float* wsum    = (float*)carve((size_t)NN * 4);
    int*   bsum    = (int*)carve(64 * 4);
    float* pooled  = (float*)carve((size_t)GN * HD * 4);
    int*   gstart  = (int*)carve((size_t)(GN + 1) * 4);
    float* stats   = (float*)carve(2 * HD * 4);
    float* affa    = (float*)carve(HD * 4);
    float* affc    = (float*)carve(HD * 4);
    float* z1      = (float*)carve((size_t)GN * HD * 4);
    float* z2      = (float*)carve((size_t)GN * (HD / 2) * 4);
    unsigned short* W1t = (unsigned short*)carve((size_t)FD * HD * 2);
    unsigned short* W2t = (unsigned short*)carve((size_t)HD * HD * 2);
    unsigned short* W3t = (unsigned short*)carve((size_t)HD * HD * 2);
    (void)ws_size;

    const int TB = 256;
    const int ebk = (NE + TB - 1) / TB;
    const int nbk = (NN + TB - 1) / TB;
    const int scanblk = (NN + 1023) / 1024;
    const int mmg = (NN + 127) / 128;       // 391

    // weight + input casts
    k_castW<<<(FD * HD + 255) / 256, 256, 0, stream>>>(W1, W1t, FD);
    k_castW<<<(HD * HD + 255) / 256, 256, 0, stream>>>(W2, W2t, HD);
    k_castW<<<(HD * HD + 255) / 256, 256, 0, stream>>>(W3, W3t, HD);
    k_castx<<<(NN * (FD / 2) + 255) / 256, 256, 0, stream>>>(x, xb);

    // degree + CSR
    hipMemsetAsync(counts, 0, (size_t)NN * 4, stream);
    k_deg<<<ebk, TB, 0, stream>>>(edst, counts);
    k_dis<<<nbk, TB, 0, stream>>>(counts, dis);
    k_scan1<<<scanblk, 1024, 0, stream>>>(counts, rowptr, bsum);
    k_scan2<<<1, 64, 0, stream>>>(bsum, rowptr, scanblk);
    k_scan3<<<nbk, TB, 0, stream>>>(rowptr, bsum);
    hipMemsetAsync(fill, 0, (size_t)NN * 4, stream);
    k_csr<<<ebk, TB, 0, stream>>>(esrc, edst, rowptr, fill, dis, csr_src, csr_w);
    k_wsum<<<nbk, TB, 0, stream>>>(rowptr, csr_w, dis, wsum);

    // layer 1: agg(x) -> GEMM(+b1,relu) -> t1 bf16; BN1 stats->affine
    k_aggb<FD, false><<<NN / 4, TB, 0, stream>>>(xb, rowptr, csr_src, csr_w, dis,
                                                 nullptr, nullptr, nullptr, xa);
    k_mmf<FD, true><<<mmg, TB, 0, stream>>>(xa, W1t, b1, tbuf);
    hipMemsetAsync(stats, 0, 2 * HD * 4, stream);
    k_statsb<<<256, TB, 0, stream>>>(tbuf, stats);
    k_affine<<<1, HD, 0, stream>>>(stats, g1, be1, affa, affc);

    // layer 2: aggBN(t1) -> GEMM(+b2,relu) -> t2 bf16; BN2 stats->affine
    k_aggb<HD, true><<<NN / 2, TB, 0, stream>>>(tbuf, rowptr, csr_src, csr_w, dis,
                                                affa, affc, wsum, ah);
    k_mmf<HD, true><<<mmg, TB, 0, stream>>>(ah, W2t, b2, tbuf);
    hipMemsetAsync(stats, 0, 2 * HD * 4, stream);
    k_statsb<<<256, TB, 0, stream>>>(tbuf, stats);
    k_affine<<<1, HD, 0, stream>>>(stats, g2, be2, affa, affc);

    // layer 3: aggBN(t2) -> GEMM(+b3,relu) -> t3 fp32
    k_aggb<HD, true><<<NN / 2, TB, 0, stream>>>(tbuf, rowptr, csr_src, csr_w, dis,
                                                affa, affc, wsum, ah);
    k_mmf<HD, false><<<mmg, TB, 0, stream>>>(ah, W3t, b3, cur);

    // pool
    hipMemsetAsync(pooled, 0, (size_t)GN * HD * 4, stream);
    k_bounds<<<1, 64, 0, stream>>>(batch, gstart);
    k_pool<<<nbk, TB, 0, stream>>>(cur, batch, pooled);
    k_poolfin<<<(GN * HD + TB - 1) / TB, TB, 0, stream>>>(pooled, gstart);

    // head
    k_head1<<<GN, TB, 0, stream>>>(pooled, actions, fW1, fb1, z1);
    k_headbn<<<1, TB, 0, stream>>>(z1, g3, be3);
    k_head2<<<GN, 128, 0, stream>>>(z1, fW2, fb2, z2);
    k_head3<<<1, 64, 0, stream>>>(z2, fW3, fb3, out);
}

// Round 5
// 604.533 us; speedup vs baseline: 2.2209x; 1.0272x over previous
//
#include <hip/hip_runtime.h>

#define NN 50000      // nodes
#define NP1 (NN + 1)  // +1 virtual zero row for even-padding
#define NE 800000     // edges
#define FD 128        // input feature dim
#define HD 256        // hidden dim
#define AD 32         // action dim
#define GN 50         // graphs
#define BN_EPS 1e-5f

typedef float f32x4 __attribute__((ext_vector_type(4)));
typedef short s16x8 __attribute__((ext_vector_type(8)));

__device__ inline unsigned short f2bf(float f) {
    unsigned u = __float_as_uint(f);
    u += 0x7FFF + ((u >> 16) & 1);   // round-to-nearest-even
    return (unsigned short)(u >> 16);
}
__device__ inline float bflo(unsigned u) { return __uint_as_float(u << 16); }
__device__ inline float bfhi(unsigned u) { return __uint_as_float(u & 0xffff0000u); }

// ---------------- degree / CSR build ----------------

__global__ void k_deg(const int* __restrict__ dst, int* __restrict__ counts) {
    int e = blockIdx.x * blockDim.x + threadIdx.x;
    if (e < NE) atomicAdd(&counts[dst[e]], 1);
}

__global__ void k_dis(const int* __restrict__ counts, float* __restrict__ dis,
                      float* __restrict__ rdis) {
    int i = blockIdx.x * blockDim.x + threadIdx.x;
    if (i < NN) {
        float dg = 1.0f + (float)counts[i];
        dis[i] = rsqrtf(dg);
        rdis[i] = sqrtf(dg);
    }
    if (i == 0) dis[NN] = 0.0f;   // virtual zero row: zero contribution via dis
}

// scan over EVEN-ROUNDED counts (each CSR row padded to even length)
__global__ void k_scan1(const int* __restrict__ counts, int* __restrict__ rowptr,
                        int* __restrict__ bsum) {
    __shared__ int s[1024];
    int t = threadIdx.x;
    int i = blockIdx.x * 1024 + t;
    int v = (i < NN) ? ((counts[i] + 1) & ~1) : 0;
    s[t] = v;
    __syncthreads();
    for (int off = 1; off < 1024; off <<= 1) {
        int u = (t >= off) ? s[t - off] : 0;
        __syncthreads();
        s[t] += u;
        __syncthreads();
    }
    if (i < NN) rowptr[i + 1] = s[t];
    if (t == 1023) bsum[blockIdx.x] = s[1023];
}

__global__ void k_scan2(int* __restrict__ bsum, int* __restrict__ rowptr, int nblk) {
    if (threadIdx.x == 0 && blockIdx.x == 0) {
        int run = 0;
        for (int b = 0; b < nblk; ++b) { int t = bsum[b]; bsum[b] = run; run += t; }
        rowptr[0] = 0;
    }
}

__global__ void k_scan3(int* __restrict__ rowptr, const int* __restrict__ bsum) {
    int i = blockIdx.x * blockDim.x + threadIdx.x;
    if (i < NN) rowptr[i + 1] += bsum[i >> 10];
}

__global__ void k_csr(const int* __restrict__ src, const int* __restrict__ dst,
                      const int* __restrict__ rowptr, int* __restrict__ fill,
                      unsigned short* __restrict__ csru) {
    int e = blockIdx.x * blockDim.x + threadIdx.x;
    if (e < NE) {
        int d = dst[e];
        int p = rowptr[d] + atomicAdd(&fill[d], 1);
        csru[p] = (unsigned short)src[e];
    }
}

// pad odd-degree rows with virtual node NN (zero row)
__global__ void k_pad(const int* __restrict__ counts, const int* __restrict__ rowptr,
                      unsigned short* __restrict__ csru) {
    int n = blockIdx.x * 256 + threadIdx.x;
    if (n < NN) {
        int c = counts[n];
        if (c & 1) csru[rowptr[n] + c] = (unsigned short)NN;
    }
}

// dsum[n] = dis_n + sum_e dis[src_e]   (agg of ones, for BN affine fold)
__global__ void k_dsum(const int* __restrict__ rowptr, const unsigned short* __restrict__ csru,
                       const float* __restrict__ dis, float* __restrict__ dsum) {
    int n = blockIdx.x * 256 + threadIdx.x;
    if (n < NN) {
        float s = dis[n];
        int e1 = rowptr[n + 1];
        for (int e = rowptr[n]; e < e1; ++e) s += dis[csru[e]];
        dsum[n] = s;
    }
}

// ---------------- casts ----------------

__global__ void k_castW(const float* __restrict__ W, unsigned short* __restrict__ Wt, int K) {
    int idx = blockIdx.x * 256 + threadIdx.x;
    if (idx < K * HD) {
        int c = idx / K, k = idx - c * K;
        Wt[idx] = f2bf(W[(size_t)k * HD + c]);
    }
}

// x fp32 [n][FD] -> chunked bf16-packed [4][NP1][16 uints], scaled by dis[n]
__global__ void k_castx(const float* __restrict__ x, const float* __restrict__ dis,
                        unsigned* __restrict__ xb) {
    int idx = blockIdx.x * 256 + threadIdx.x;   // over NN*64 uints
    if (idx < NN * (FD / 2)) {
        int n = idx >> 6, jj = idx & 63;
        int chunk = jj >> 4, w = jj & 15;
        float sc = dis[n];
        float2 v = *(const float2*)&x[(size_t)n * FD + jj * 2];
        xb[((size_t)chunk * NP1 + n) * 16 + w] =
            ((unsigned)f2bf(v.y * sc) << 16) | f2bf(v.x * sc);
    }
}

// zero the virtual pad row (row NN) of xb (4 chunks) and tbuf (8 chunks)
__global__ void k_zrow(unsigned* __restrict__ xb, unsigned* __restrict__ tbuf) {
    int t = threadIdx.x;    // 192 threads
    if (t < 64) xb[((size_t)(t >> 4) * NP1 + NN) * 16 + (t & 15)] = 0;
    else if (t < 192) {
        int q = t - 64;
        tbuf[((size_t)(q >> 4) * NP1 + NN) * 16 + (q & 15)] = 0;
    }
}

// ---------------- MFMA bf16 GEMM: C = A @ W, bias+relu ----------------
// A chunked bf16-packed [K/32][NP1][16 uints]; Wt bf16 [HD][K].
// BF16OUT: write chunked bf16 [8][NP1][32 ushorts], scaled by dis[row];
// else plain fp32 [row][HD].

template<int K, bool BF16OUT>
__global__ __launch_bounds__(256) void k_mmf(const unsigned* __restrict__ Ab,
                                             const unsigned short* __restrict__ Wt,
                                             const float* __restrict__ bias,
                                             const float* __restrict__ dis,
                                             void* __restrict__ Cout) {
    __shared__ __align__(16) short Als[128 * 40];   // [row][k] stride 40 shorts
    __shared__ __align__(16) short Bls[256 * 40];   // [col][k]
    int t = threadIdx.x;
    int rowBase = blockIdx.x * 128;
    int wid = t >> 6, lane = t & 63;
    int lr = lane & 15, kg = (lane >> 4) * 8;

    f32x4 acc[2][16];
#pragma unroll
    for (int i = 0; i < 2; ++i)
#pragma unroll
        for (int j = 0; j < 16; ++j) acc[i][j] = (f32x4){0.f, 0.f, 0.f, 0.f};

    for (int k0 = 0; k0 < K; k0 += 32) {
        const unsigned* ap = Ab + (size_t)(k0 >> 5) * NP1 * 16;
        // stage A: 128 rows x 32 k bf16 (copy)
#pragma unroll
        for (int it = 0; it < 2; ++it) {
            int task = t + it * 256;          // 0..511
            int row = task >> 2, k8 = (task & 3) * 8;
            int grow = rowBase + row;
            s16x8 v = (s16x8)(short)0;
            if (grow < NN)
                v = *(const s16x8*)&ap[grow * 16 + (task & 3) * 4];
            *(s16x8*)&Als[row * 40 + k8] = v;
        }
        // stage B: 256 cols x 32 k
#pragma unroll
        for (int it = 0; it < 4; ++it) {
            int task = t + it * 256;          // 0..1023
            int col = task >> 2, k8 = (task & 3) * 8;
            *(s16x8*)&Bls[col * 40 + k8] = *(const s16x8*)&Wt[(size_t)col * K + k0 + k8];
        }
        __syncthreads();
        s16x8 a0 = *(const s16x8*)&Als[(wid * 32 + lr) * 40 + kg];
        s16x8 a1 = *(const s16x8*)&Als[(wid * 32 + 16 + lr) * 40 + kg];
#pragma unroll
        for (int nf = 0; nf < 16; ++nf) {
            s16x8 b = *(const s16x8*)&Bls[(nf * 16 + lr) * 40 + kg];
            acc[0][nf] = __builtin_amdgcn_mfma_f32_16x16x32_bf16(a0, b, acc[0][nf], 0, 0, 0);
            acc[1][nf] = __builtin_amdgcn_mfma_f32_16x16x32_bf16(a1, b, acc[1][nf], 0, 0, 0);
        }
        __syncthreads();
    }

    int r4 = (lane >> 4) * 4;
#pragma unroll
    for (int mf = 0; mf < 2; ++mf) {
#pragma unroll
        for (int r = 0; r < 4; ++r) {
            int row = rowBase + wid * 32 + mf * 16 + r4 + r;
            if (row < NN) {
                float sc = BF16OUT ? dis[row] : 1.0f;
#pragma unroll
                for (int nf = 0; nf < 16; ++nf) {
                    int col = nf * 16 + lr;
                    float vv = fmaxf(acc[mf][nf][r] + bias[col], 0.f);
                    if (BF16OUT)
                        ((unsigned short*)Cout)[((size_t)(col >> 5) * NP1 + row) * 32 + (col & 31)]
                            = f2bf(vv * sc);
                    else
                        ((float*)Cout)[(size_t)row * HD + col] = vv;
                }
            }
        }
    }
}

// ---------------- chunked GCN aggregate (+optional BN affine fold) ----------------
// in: t' = dis ⊙ t, chunked [NCHUNK][NP1][16 uints].  S = t'[n] + Σ_e t'[src].
// out = dis_n * (a⊙S + c*dsum_n)  (AFFINE)  or  dis_n * S.
// chunk = blockIdx & (NCHUNK-1): consecutive blocks -> different XCDs (round-robin)
// pins each chunk's 3.2 MB slice in one XCD's L2.

template<int NCHUNK, bool AFFINE>
__global__ __launch_bounds__(256) void k_aggc(const unsigned* __restrict__ tin,
                                              const int* __restrict__ rowptr,
                                              const unsigned short* __restrict__ csru,
                                              const float* __restrict__ dis,
                                              const float* __restrict__ aff_a,
                                              const float* __restrict__ aff_c,
                                              const float* __restrict__ dsum,
                                              unsigned* __restrict__ outp) {
    int c = blockIdx.x & (NCHUNK - 1);
    int g = blockIdx.x / NCHUNK;
    int local = threadIdx.x >> 4;        // 16 nodes per block
    int jj = threadIdx.x & 15;           // uint within chunk
    int n = g * 16 + local;
    if (n >= NN) return;
    const unsigned* tc = tin + (size_t)c * NP1 * 16;
    unsigned u0 = tc[n * 16 + jj];
    float acc0 = bflo(u0), acc1 = bfhi(u0);
    int e0 = rowptr[n], e1 = rowptr[n + 1];   // even-aligned, even length
    int e = e0;
    for (; e + 8 <= e1; e += 8) {
        const unsigned* p32 = (const unsigned*)(csru + e);
        unsigned i01 = p32[0], i23 = p32[1], i45 = p32[2], i67 = p32[3];
        unsigned v0 = tc[(i01 & 0xffffu) * 16 + jj];
        unsigned v1 = tc[(i01 >> 16) * 16 + jj];
        unsigned v2 = tc[(i23 & 0xffffu) * 16 + jj];
        unsigned v3 = tc[(i23 >> 16) * 16 + jj];
        unsigned v4 = tc[(i45 & 0xffffu) * 16 + jj];
        unsigned v5 = tc[(i45 >> 16) * 16 + jj];
        unsigned v6 = tc[(i67 & 0xffffu) * 16 + jj];
        unsigned v7 = tc[(i67 >> 16) * 16 + jj];
        acc0 += bflo(v0); acc1 += bfhi(v0);
        acc0 += bflo(v1); acc1 += bfhi(v1);
        acc0 += bflo(v2); acc1 += bfhi(v2);
        acc0 += bflo(v3); acc1 += bfhi(v3);
        acc0 += bflo(v4); acc1 += bfhi(v4);
        acc0 += bflo(v5); acc1 += bfhi(v5);
        acc0 += bflo(v6); acc1 += bfhi(v6);
        acc0 += bflo(v7); acc1 += bfhi(v7);
    }
    for (; e < e1; e += 2) {
        unsigned i01 = *(const unsigned*)(csru + e);
        unsigned v0 = tc[(i01 & 0xffffu) * 16 + jj];
        unsigned v1 = tc[(i01 >> 16) * 16 + jj];
        acc0 += bflo(v0) + bflo(v1);
        acc1 += bfhi(v0) + bfhi(v1);
    }
    float dn = dis[n];
    if (AFFINE) {
        float wn = dsum[n];
        int col2 = c * 16 + jj;
        float2 a2 = *(const float2*)&aff_a[2 * col2];
        float2 c2 = *(const float2*)&aff_c[2 * col2];
        acc0 = dn * fmaf(a2.x, acc0, c2.x * wn);
        acc1 = dn * fmaf(a2.y, acc1, c2.y * wn);
    } else {
        acc0 *= dn;
        acc1 *= dn;
    }
    outp[((size_t)c * NP1 + n) * 16 + jj] = ((unsigned)f2bf(acc1) << 16) | f2bf(acc0);
}

// ---------------- batchnorm stats on chunked t' (recover t = t' * rdis) ----------------

__global__ __launch_bounds__(256) void k_statsb(const unsigned* __restrict__ t,
                                                const float* __restrict__ rdis,
                                                float* __restrict__ stats) {
    int jj = threadIdx.x & 127, half = threadIdx.x >> 7;
    int chunk = jj >> 4, w = jj & 15;
    const unsigned* tc = t + (size_t)chunk * NP1 * 16;
    int rows_per = (NN + gridDim.x - 1) / gridDim.x;
    int r0 = blockIdx.x * rows_per;
    int r1 = min(r0 + rows_per, NN);
    float s0 = 0.f, q0 = 0.f, s1 = 0.f, q1 = 0.f;
    for (int r = r0 + half; r < r1; r += 2) {
        unsigned u = tc[r * 16 + w];
        float rd = rdis[r];
        float v0 = bflo(u) * rd, v1 = bfhi(u) * rd;
        s0 += v0; q0 = fmaf(v0, v0, q0);
        s1 += v1; q1 = fmaf(v1, v1, q1);
    }
    atomicAdd(&stats[2 * jj], s0);
    atomicAdd(&stats[2 * jj + 1], s1);
    atomicAdd(&stats[HD + 2 * jj], q0);
    atomicAdd(&stats[HD + 2 * jj + 1], q1);
}

__global__ void k_affine(const float* __restrict__ stats, const float* __restrict__ g,
                         const float* __restrict__ be, float* __restrict__ a,
                         float* __restrict__ c) {
    int j = threadIdx.x;
    float mu = stats[j] * (1.0f / NN);
    float var = stats[HD + j] * (1.0f / NN) - mu * mu;
    float rs = rsqrtf(var + BN_EPS);
    float aj = g[j] * rs;
    a[j] = aj;
    c[j] = be[j] - mu * aj;
}

// ---------------- global mean pool (sorted batch -> segments) ----------------

__global__ void k_bounds(const int* __restrict__ batch, int* __restrict__ gstart) {
    int g = threadIdx.x;
    if (g <= GN) {
        int lo = 0, hi = NN;
        while (lo < hi) {
            int mid = (lo + hi) >> 1;
            if (batch[mid] < g) lo = mid + 1; else hi = mid;
        }
        gstart[g] = lo;
    }
}

__global__ __launch_bounds__(256) void k_pool(const float* __restrict__ h,
                                              const int* __restrict__ batch,
                                              float* __restrict__ pooled) {
    int r0 = blockIdx.x * 256;
    int r1 = min(r0 + 256, NN);
    int j = threadIdx.x;
    float acc = 0.f;
    int curg = batch[r0];
    for (int r = r0; r < r1; ++r) {
        int g = batch[r];
        if (g != curg) {
            atomicAdd(&pooled[(size_t)curg * HD + j], acc);
            acc = 0.f;
            curg = g;
        }
        acc += h[(size_t)r * HD + j];
    }
    atomicAdd(&pooled[(size_t)curg * HD + j], acc);
}

__global__ void k_poolfin(float* __restrict__ pooled, const int* __restrict__ gstart) {
    int idx = blockIdx.x * blockDim.x + threadIdx.x;
    if (idx < GN * HD) {
        int g = idx >> 8;
        float c = (float)max(gstart[g + 1] - gstart[g], 1);
        pooled[idx] /= c;
    }
}

// ---------------- MLP head ----------------

__global__ __launch_bounds__(256) void k_head1(const float* __restrict__ pooled,
                                               const float* __restrict__ actions,
                                               const float* __restrict__ fW1,
                                               const float* __restrict__ fb1,
                                               float* __restrict__ z1) {
    int g = blockIdx.x, j = threadIdx.x;
    float acc = fb1[j];
    for (int k = 0; k < HD; ++k)
        acc = fmaf(pooled[g * HD + k], fW1[k * HD + j], acc);
    for (int k = 0; k < AD; ++k)
        acc = fmaf(actions[k], fW1[(HD + k) * HD + j], acc);
    z1[g * HD + j] = fmaxf(acc, 0.f);
}

__global__ __launch_bounds__(256) void k_headbn(float* __restrict__ z1,
                                                const float* __restrict__ g3,
                                                const float* __restrict__ be3) {
    int j = threadIdx.x;
    float s = 0.f, q = 0.f;
    for (int g = 0; g < GN; ++g) {
        float v = z1[g * HD + j];
        s += v;
        q = fmaf(v, v, q);
    }
    float mu = s * (1.0f / GN);
    float var = q * (1.0f / GN) - mu * mu;
    float rs = rsqrtf(var + BN_EPS);
    float ga = g3[j], be = be3[j];
    for (int g = 0; g < GN; ++g)
        z1[g * HD + j] = fmaf((z1[g * HD + j] - mu) * rs, ga, be);
}

__global__ __launch_bounds__(128) void k_head2(const float* __restrict__ z1,
                                               const float* __restrict__ fW2,
                                               const float* __restrict__ fb2,
                                               float* __restrict__ z2) {
    int g = blockIdx.x, j = threadIdx.x;
    float acc = fb2[j];
    for (int k = 0; k < HD; ++k)
        acc = fmaf(z1[g * HD + k], fW2[k * (HD / 2) + j], acc);
    z2[g * (HD / 2) + j] = fmaxf(acc, 0.f);
}

__global__ __launch_bounds__(64) void k_head3(const float* __restrict__ z2,
                                              const float* __restrict__ fW3,
                                              const float* __restrict__ fb3,
                                              float* __restrict__ out) {
    int g = threadIdx.x;
    if (g < GN) {
        float acc = fb3[0];
        for (int k = 0; k < HD / 2; ++k)
            acc = fmaf(z2[g * (HD / 2) + k], fW3[k], acc);
        out[g] = acc;
    }
}

// ---------------- launch ----------------

static inline size_t align256(size_t x) { return (x + 255) & ~(size_t)255; }

extern "C" void kernel_launch(void* const* d_in, const int* in_sizes, int n_in,
                              void* d_out, int out_size, void* d_ws, size_t ws_size,
                              hipStream_t stream) {
    const float* x       = (const float*)d_in[0];
    const int*   ei      = (const int*)d_in[1];
    const int*   batch   = (const int*)d_in[2];
    const float* actions = (const float*)d_in[3];
    const float* W1 = (const float*)d_in[4];
    const float* b1 = (const float*)d_in[5];
    const float* W2 = (const float*)d_in[6];
    const float* b2 = (const float*)d_in[7];
    const float* W3 = (const float*)d_in[8];
    const float* b3 = (const float*)d_in[9];
    const float* g1  = (const float*)d_in[10];
    const float* be1 = (const float*)d_in[11];
    const float* g2  = (const float*)d_in[12];
    const float* be2 = (const float*)d_in[13];
    const float* g3  = (const float*)d_in[14];
    const float* be3 = (const float*)d_in[15];
    const float* fW1 = (const float*)d_in[16];
    const float* fb1 = (const float*)d_in[17];
    const float* fW2 = (const float*)d_in[18];
    const float* fb2 = (const float*)d_in[19];
    const float* fW3 = (const float*)d_in[20];
    const float* fb3 = (const float*)d_in[21];
    float* out = (float*)d_out;

    const int* esrc = ei;
    const int* edst = ei + NE;

    // workspace carve
    char* p = (char*)d_ws;
    size_t off = 0;
    auto carve = [&](size_t bytes) { void* r = p + off; off = align256(off + bytes); return r; };
    unsigned* xb   = (unsigned*)carve((size_t)4 * NP1 * 16 * 4);    // x' chunked bf16
    unsigned* xa   = (unsigned*)carve((size_t)4 * NP1 * 16 * 4);    // agg(x') chunked
    unsigned* tbuf = (unsigned*)carve((size_t)8 * NP1 * 16 * 4);    // t1'/t2' chunked
    unsigned* ah   = (unsigned*)carve((size_t)8 * NP1 * 16 * 4);    // agg outputs chunked
    float* cur     = (float*)carve((size_t)NN * HD * 4);            // t3 fp32 plain
    float* dis     = (float*)carve((size_t)NP1 * 4);
    float* rdis    = (float*)carve((size_t)NN * 4);
    int*   counts  = (int*)carve((size_t)NN * 4);
    int*   rowptr  = (int*)carve((size_t)(NN + 1) * 4);
    int*   fill    = (int*)carve((size_t)NN * 4);
    unsigned short* csru = (unsigned short*)carve((size_t)(NE + NN) * 2);
    float* dsum    = (float*)carve((size_t)NN * 4);
    int*   bsum    = (int*)carve(64 * 4);
    float* pooled  = (float*)carve((size_t)GN * HD * 4);
    int*   gstart  = (int*)carve((size_t)(GN + 1) * 4);
    float* stats   = (float*)carve(2 * HD * 4);
    float* affa    = (float*)carve(HD * 4);
    float* affc    = (float*)carve(HD * 4);
    float* z1      = (float*)carve((size_t)GN * HD * 4);
    float* z2      = (float*)carve((size_t)GN * (HD / 2) * 4);
    unsigned short* W1t = (unsigned short*)carve((size_t)FD * HD * 2);
    unsigned short* W2t = (unsigned short*)carve((size_t)HD * HD * 2);
    unsigned short* W3t = (unsigned short*)carve((size_t)HD * HD * 2);
    (void)ws_size;

    const int TB = 256;
    const int ebk = (NE + TB - 1) / TB;
    const int nbk = (NN + TB - 1) / TB;
    const int scanblk = (NN + 1023) / 1024;
    const int mmg = (NN + 127) / 128;       // 391
    const int ngrp = NN / 16;               // 3125 node groups for agg

    // weight casts
    k_castW<<<(FD * HD + 255) / 256, 256, 0, stream>>>(W1, W1t, FD);
    k_castW<<<(HD * HD + 255) / 256, 256, 0, stream>>>(W2, W2t, HD);
    k_castW<<<(HD * HD + 255) / 256, 256, 0, stream>>>(W3, W3t, HD);

    // degree + CSR (ushort, even-padded rows)
    hipMemsetAsync(counts, 0, (size_t)NN * 4, stream);
    k_deg<<<ebk, TB, 0, stream>>>(edst, counts);
    k_dis<<<nbk, TB, 0, stream>>>(counts, dis, rdis);
    k_scan1<<<scanblk, 1024, 0, stream>>>(counts, rowptr, bsum);
    k_scan2<<<1, 64, 0, stream>>>(bsum, rowptr, scanblk);
    k_scan3<<<nbk, TB, 0, stream>>>(rowptr, bsum);
    hipMemsetAsync(fill, 0, (size_t)NN * 4, stream);
    k_csr<<<ebk, TB, 0, stream>>>(esrc, edst, rowptr, fill, csru);
    k_pad<<<nbk, TB, 0, stream>>>(counts, rowptr, csru);
    k_dsum<<<nbk, TB, 0, stream>>>(rowptr, csru, dis, dsum);

    // input cast (chunked, dis-scaled) + zero pad rows
    k_castx<<<(NN * (FD / 2) + 255) / 256, 256, 0, stream>>>(x, dis, xb);
    k_zrow<<<1, 192, 0, stream>>>(xb, tbuf);

    // layer 1: agg(x') -> GEMM(+b1,relu,*dis) -> t1' chunked; BN1 stats->affine
    k_aggc<4, false><<<4 * ngrp, TB, 0, stream>>>(xb, rowptr, csru, dis,
                                                  nullptr, nullptr, nullptr, xa);
    k_mmf<FD, true><<<mmg, TB, 0, stream>>>(xa, W1t, b1, dis, tbuf);
    hipMemsetAsync(stats, 0, 2 * HD * 4, stream);
    k_statsb<<<256, TB, 0, stream>>>(tbuf, rdis, stats);
    k_affine<<<1, HD, 0, stream>>>(stats, g1, be1, affa, affc);

    // layer 2: aggBN(t1') -> GEMM(+b2,relu,*dis) -> t2' chunked; BN2 stats->affine
    k_aggc<8, true><<<8 * ngrp, TB, 0, stream>>>(tbuf, rowptr, csru, dis,
                                                 affa, affc, dsum, ah);
    k_mmf<HD, true><<<mmg, TB, 0, stream>>>(ah, W2t, b2, dis, tbuf);
    hipMemsetAsync(stats, 0, 2 * HD * 4, stream);
    k_statsb<<<256, TB, 0, stream>>>(tbuf, rdis, stats);
    k_affine<<<1, HD, 0, stream>>>(stats, g2, be2, affa, affc);

    // layer 3: aggBN(t2') -> GEMM(+b3,relu) -> t3 fp32 plain
    k_aggc<8, true><<<8 * ngrp, TB, 0, stream>>>(tbuf, rowptr, csru, dis,
                                                 affa, affc, dsum, ah);
    k_mmf<HD, false><<<mmg, TB, 0, stream>>>(ah, W3t, b3, dis, cur);

    // pool
    hipMemsetAsync(pooled, 0, (size_t)GN * HD * 4, stream);
    k_bounds<<<1, 64, 0, stream>>>(batch, gstart);
    k_pool<<<nbk, TB, 0, stream>>>(cur, batch, pooled);
    k_poolfin<<<(GN * HD + TB - 1) / TB, TB, 0, stream>>>(pooled, gstart);

    // head
    k_head1<<<GN, TB, 0, stream>>>(pooled, actions, fW1, fb1, z1);
    k_headbn<<<1, TB, 0, stream>>>(z1, g3, be3);
    k_head2<<<GN, 128, 0, stream>>>(z1, fW2, fb2, z2);
    k_head3<<<1, 64, 0, stream>>>(z2, fW3, fb3, out);
}

// Round 6
// 510.019 us; speedup vs baseline: 2.6324x; 1.1853x over previous
//
#include <hip/hip_runtime.h>

#define NN 50000      // nodes
#define NP1 (NN + 1)  // +1 virtual zero row for even-padding
#define NE 800000     // edges
#define FD 128        // input feature dim
#define HD 256        // hidden dim
#define AD 32         // action dim
#define GN 50         // graphs
#define BN_EPS 1e-5f

#define EPI_STATS 0   // bf16 chunked out + fused BN stats
#define EPI_POOL  1   // no tensor out; fused graph mean-pool (sums)

typedef float f32x4 __attribute__((ext_vector_type(4)));
typedef short s16x8 __attribute__((ext_vector_type(8)));

__device__ inline unsigned short f2bf(float f) {
    unsigned u = __float_as_uint(f);
    u += 0x7FFF + ((u >> 16) & 1);   // round-to-nearest-even
    return (unsigned short)(u >> 16);
}
__device__ inline float bflo(unsigned u) { return __uint_as_float(u << 16); }
__device__ inline float bfhi(unsigned u) { return __uint_as_float(u & 0xffff0000u); }

// ---------------- degree / CSR build ----------------

__global__ void k_deg(const int* __restrict__ dst, int* __restrict__ counts) {
    int e = blockIdx.x * blockDim.x + threadIdx.x;
    if (e < NE) atomicAdd(&counts[dst[e]], 1);
}

__global__ void k_dis(const int* __restrict__ counts, float* __restrict__ dis,
                      float* __restrict__ rdis) {
    int i = blockIdx.x * blockDim.x + threadIdx.x;
    if (i < NN) {
        float dg = 1.0f + (float)counts[i];
        dis[i] = rsqrtf(dg);
        rdis[i] = sqrtf(dg);
    }
    if (i == 0) dis[NN] = 0.0f;
}

__global__ void k_scan1(const int* __restrict__ counts, int* __restrict__ rowptr,
                        int* __restrict__ bsum) {
    __shared__ int s[1024];
    int t = threadIdx.x;
    int i = blockIdx.x * 1024 + t;
    int v = (i < NN) ? ((counts[i] + 1) & ~1) : 0;
    s[t] = v;
    __syncthreads();
    for (int off = 1; off < 1024; off <<= 1) {
        int u = (t >= off) ? s[t - off] : 0;
        __syncthreads();
        s[t] += u;
        __syncthreads();
    }
    if (i < NN) rowptr[i + 1] = s[t];
    if (t == 1023) bsum[blockIdx.x] = s[1023];
}

__global__ void k_scan2(int* __restrict__ bsum, int* __restrict__ rowptr, int nblk) {
    if (threadIdx.x == 0 && blockIdx.x == 0) {
        int run = 0;
        for (int b = 0; b < nblk; ++b) { int t = bsum[b]; bsum[b] = run; run += t; }
        rowptr[0] = 0;
    }
}

__global__ void k_scan3(int* __restrict__ rowptr, const int* __restrict__ bsum) {
    int i = blockIdx.x * blockDim.x + threadIdx.x;
    if (i < NN) rowptr[i + 1] += bsum[i >> 10];
}

__global__ void k_csr(const int* __restrict__ src, const int* __restrict__ dst,
                      const int* __restrict__ rowptr, int* __restrict__ fill,
                      unsigned short* __restrict__ csru) {
    int e = blockIdx.x * blockDim.x + threadIdx.x;
    if (e < NE) {
        int d = dst[e];
        int p = rowptr[d] + atomicAdd(&fill[d], 1);
        csru[p] = (unsigned short)src[e];
    }
}

__global__ void k_pad(const int* __restrict__ counts, const int* __restrict__ rowptr,
                      unsigned short* __restrict__ csru) {
    int n = blockIdx.x * 256 + threadIdx.x;
    if (n < NN) {
        int c = counts[n];
        if (c & 1) csru[rowptr[n] + c] = (unsigned short)NN;
    }
}

__global__ void k_dsum(const int* __restrict__ rowptr, const unsigned short* __restrict__ csru,
                       const float* __restrict__ dis, float* __restrict__ dsum) {
    int n = blockIdx.x * 256 + threadIdx.x;
    if (n < NN) {
        float s = dis[n];
        int e1 = rowptr[n + 1];
        for (int e = rowptr[n]; e < e1; ++e) s += dis[csru[e]];
        dsum[n] = s;
    }
}

// ---------------- casts ----------------

__global__ void k_castW(const float* __restrict__ W, unsigned short* __restrict__ Wt, int K) {
    int idx = blockIdx.x * 256 + threadIdx.x;
    if (idx < K * HD) {
        int c = idx / K, k = idx - c * K;
        Wt[idx] = f2bf(W[(size_t)k * HD + c]);
    }
}

__global__ void k_castx(const float* __restrict__ x, const float* __restrict__ dis,
                        unsigned* __restrict__ xb) {
    int idx = blockIdx.x * 256 + threadIdx.x;
    if (idx < NN * (FD / 2)) {
        int n = idx >> 6, jj = idx & 63;
        int chunk = jj >> 4, w = jj & 15;
        float sc = dis[n];
        float2 v = *(const float2*)&x[(size_t)n * FD + jj * 2];
        xb[((size_t)chunk * NP1 + n) * 16 + w] =
            ((unsigned)f2bf(v.y * sc) << 16) | f2bf(v.x * sc);
    }
}

__global__ void k_zrow(unsigned* __restrict__ xb, unsigned* __restrict__ tbuf) {
    int t = threadIdx.x;    // 192 threads
    if (t < 64) xb[((size_t)(t >> 4) * NP1 + NN) * 16 + (t & 15)] = 0;
    else if (t < 192) {
        int q = t - 64;
        tbuf[((size_t)(q >> 4) * NP1 + NN) * 16 + (q & 15)] = 0;
    }
}

// ---------------- MFMA bf16 GEMM with fused epilogue ----------------
// A chunked bf16-packed [K/32][NP1][16 uints]; Wt bf16 [HD][K].
// EPI_STATS: write t' = dis*relu(acc+bias) chunked bf16 AND accumulate
//            stats[col] += sum(v), stats[HD+col] += sum(v^2).
// EPI_POOL : no tensor write; pooled[batch[row]][col] += v (graph sums).

template<int K, int EPI>
__global__ __launch_bounds__(256) void k_mmf(const unsigned* __restrict__ Ab,
                                             const unsigned short* __restrict__ Wt,
                                             const float* __restrict__ bias,
                                             const float* __restrict__ dis,
                                             unsigned short* __restrict__ Cout,
                                             const int* __restrict__ batch,
                                             float* __restrict__ pooled,
                                             float* __restrict__ stats) {
    __shared__ __align__(16) short Als[128 * 40];   // [row][k] stride 40 shorts
    __shared__ __align__(16) short Bls[256 * 40];   // [col][k]
    int t = threadIdx.x;
    int rowBase = blockIdx.x * 128;
    int wid = t >> 6, lane = t & 63;
    int lr = lane & 15, kg = (lane >> 4) * 8;

    f32x4 acc[2][16];
#pragma unroll
    for (int i = 0; i < 2; ++i)
#pragma unroll
        for (int j = 0; j < 16; ++j) acc[i][j] = (f32x4){0.f, 0.f, 0.f, 0.f};

    for (int k0 = 0; k0 < K; k0 += 32) {
        const unsigned* ap = Ab + (size_t)(k0 >> 5) * NP1 * 16;
#pragma unroll
        for (int it = 0; it < 2; ++it) {
            int task = t + it * 256;
            int row = task >> 2, k8 = (task & 3) * 8;
            int grow = rowBase + row;
            s16x8 v = (s16x8)(short)0;
            if (grow < NN)
                v = *(const s16x8*)&ap[grow * 16 + (task & 3) * 4];
            *(s16x8*)&Als[row * 40 + k8] = v;
        }
#pragma unroll
        for (int it = 0; it < 4; ++it) {
            int task = t + it * 256;
            int col = task >> 2, k8 = (task & 3) * 8;
            *(s16x8*)&Bls[col * 40 + k8] = *(const s16x8*)&Wt[(size_t)col * K + k0 + k8];
        }
        __syncthreads();
        s16x8 a0 = *(const s16x8*)&Als[(wid * 32 + lr) * 40 + kg];
        s16x8 a1 = *(const s16x8*)&Als[(wid * 32 + 16 + lr) * 40 + kg];
#pragma unroll
        for (int nf = 0; nf < 16; ++nf) {
            s16x8 b = *(const s16x8*)&Bls[(nf * 16 + lr) * 40 + kg];
            acc[0][nf] = __builtin_amdgcn_mfma_f32_16x16x32_bf16(a0, b, acc[0][nf], 0, 0, 0);
            acc[1][nf] = __builtin_amdgcn_mfma_f32_16x16x32_bf16(a1, b, acc[1][nf], 0, 0, 0);
        }
        __syncthreads();
    }

    int r4 = (lane >> 4) * 4;
    // precompute row validity + dis scale for this thread's 8 rows
    bool okr[2][4];
    float scr[2][4];
#pragma unroll
    for (int mf = 0; mf < 2; ++mf)
#pragma unroll
        for (int r = 0; r < 4; ++r) {
            int row = rowBase + wid * 32 + mf * 16 + r4 + r;
            okr[mf][r] = row < NN;
            scr[mf][r] = (EPI == EPI_STATS && row < NN) ? dis[row] : 1.0f;
        }

    if (EPI == EPI_STATS) {
        float* ps = (float*)Als;   // 4*256 floats
        float* pq = (float*)Bls;
#pragma unroll
        for (int nf = 0; nf < 16; ++nf) {
            int col = nf * 16 + lr;
            float bcol = bias[col];
            float s_ = 0.f, q_ = 0.f;
#pragma unroll
            for (int mf = 0; mf < 2; ++mf)
#pragma unroll
                for (int r = 0; r < 4; ++r) {
                    float vv = okr[mf][r] ? fmaxf(acc[mf][nf][r] + bcol, 0.f) : 0.f;
                    s_ += vv;
                    q_ = fmaf(vv, vv, q_);
                    if (okr[mf][r]) {
                        int row = rowBase + wid * 32 + mf * 16 + r4 + r;
                        Cout[((size_t)(col >> 5) * NP1 + row) * 32 + (col & 31)]
                            = f2bf(vv * scr[mf][r]);
                    }
                }
            s_ += __shfl_xor(s_, 16); s_ += __shfl_xor(s_, 32);
            q_ += __shfl_xor(q_, 16); q_ += __shfl_xor(q_, 32);
            if (lane < 16) { ps[wid * 256 + col] = s_; pq[wid * 256 + col] = q_; }
        }
        __syncthreads();
        float ssum = ps[t] + ps[256 + t] + ps[512 + t] + ps[768 + t];
        float qsum = pq[t] + pq[256 + t] + pq[512 + t] + pq[768 + t];
        atomicAdd(&stats[t], ssum);
        atomicAdd(&stats[HD + t], qsum);
    } else {
        // EPI_POOL
        int nvalid = NN - rowBase;
        bool fast = (nvalid >= 128) && (batch[rowBase] == batch[rowBase + 127]);
        if (fast) {
            int g0 = batch[rowBase];
            float* ps = (float*)Als;
#pragma unroll
            for (int nf = 0; nf < 16; ++nf) {
                int col = nf * 16 + lr;
                float bcol = bias[col];
                float s_ = 0.f;
#pragma unroll
                for (int mf = 0; mf < 2; ++mf)
#pragma unroll
                    for (int r = 0; r < 4; ++r)
                        s_ += fmaxf(acc[mf][nf][r] + bcol, 0.f);
                s_ += __shfl_xor(s_, 16); s_ += __shfl_xor(s_, 32);
                if (lane < 16) ps[wid * 256 + col] = s_;
            }
            __syncthreads();
            float ssum = ps[t] + ps[256 + t] + ps[512 + t] + ps[768 + t];
            atomicAdd(&pooled[g0 * HD + t], ssum);
        } else {
#pragma unroll
            for (int mf = 0; mf < 2; ++mf)
#pragma unroll
                for (int r = 0; r < 4; ++r) {
                    int row = rowBase + wid * 32 + mf * 16 + r4 + r;
                    if (row < NN) {
                        int g = batch[row];
#pragma unroll
                        for (int nf = 0; nf < 16; ++nf) {
                            int col = nf * 16 + lr;
                            float vv = fmaxf(acc[mf][nf][r] + bias[col], 0.f);
                            atomicAdd(&pooled[g * HD + col], vv);
                        }
                    }
                }
        }
    }
}

// ---------------- chunked GCN aggregate (+optional BN affine fold) ----------------

template<int NCHUNK, bool AFFINE>
__global__ __launch_bounds__(256) void k_aggc(const unsigned* __restrict__ tin,
                                              const int* __restrict__ rowptr,
                                              const unsigned short* __restrict__ csru,
                                              const float* __restrict__ dis,
                                              const float* __restrict__ aff_a,
                                              const float* __restrict__ aff_c,
                                              const float* __restrict__ dsum,
                                              unsigned* __restrict__ outp) {
    int c = blockIdx.x & (NCHUNK - 1);
    int g = blockIdx.x / NCHUNK;
    int local = threadIdx.x >> 4;
    int jj = threadIdx.x & 15;
    int n = g * 16 + local;
    if (n >= NN) return;
    const unsigned* tc = tin + (size_t)c * NP1 * 16;
    unsigned u0 = tc[n * 16 + jj];
    float acc0 = bflo(u0), acc1 = bfhi(u0);
    int e0 = rowptr[n], e1 = rowptr[n + 1];
    int e = e0;
    for (; e + 8 <= e1; e += 8) {
        const unsigned* p32 = (const unsigned*)(csru + e);
        unsigned i01 = p32[0], i23 = p32[1], i45 = p32[2], i67 = p32[3];
        unsigned v0 = tc[(i01 & 0xffffu) * 16 + jj];
        unsigned v1 = tc[(i01 >> 16) * 16 + jj];
        unsigned v2 = tc[(i23 & 0xffffu) * 16 + jj];
        unsigned v3 = tc[(i23 >> 16) * 16 + jj];
        unsigned v4 = tc[(i45 & 0xffffu) * 16 + jj];
        unsigned v5 = tc[(i45 >> 16) * 16 + jj];
        unsigned v6 = tc[(i67 & 0xffffu) * 16 + jj];
        unsigned v7 = tc[(i67 >> 16) * 16 + jj];
        acc0 += bflo(v0); acc1 += bfhi(v0);
        acc0 += bflo(v1); acc1 += bfhi(v1);
        acc0 += bflo(v2); acc1 += bfhi(v2);
        acc0 += bflo(v3); acc1 += bfhi(v3);
        acc0 += bflo(v4); acc1 += bfhi(v4);
        acc0 += bflo(v5); acc1 += bfhi(v5);
        acc0 += bflo(v6); acc1 += bfhi(v6);
        acc0 += bflo(v7); acc1 += bfhi(v7);
    }
    for (; e < e1; e += 2) {
        unsigned i01 = *(const unsigned*)(csru + e);
        unsigned v0 = tc[(i01 & 0xffffu) * 16 + jj];
        unsigned v1 = tc[(i01 >> 16) * 16 + jj];
        acc0 += bflo(v0) + bflo(v1);
        acc1 += bfhi(v0) + bfhi(v1);
    }
    float dn = dis[n];
    if (AFFINE) {
        float wn = dsum[n];
        int col2 = c * 16 + jj;
        float2 a2 = *(const float2*)&aff_a[2 * col2];
        float2 c2 = *(const float2*)&aff_c[2 * col2];
        acc0 = dn * fmaf(a2.x, acc0, c2.x * wn);
        acc1 = dn * fmaf(a2.y, acc1, c2.y * wn);
    } else {
        acc0 *= dn;
        acc1 *= dn;
    }
    outp[((size_t)c * NP1 + n) * 16 + jj] = ((unsigned)f2bf(acc1) << 16) | f2bf(acc0);
}

// ---------------- BN affine from stats ----------------

__global__ void k_affine(const float* __restrict__ stats, const float* __restrict__ g,
                         const float* __restrict__ be, float* __restrict__ a,
                         float* __restrict__ c) {
    int j = threadIdx.x;
    float mu = stats[j] * (1.0f / NN);
    float var = stats[HD + j] * (1.0f / NN) - mu * mu;
    float rs = rsqrtf(var + BN_EPS);
    float aj = g[j] * rs;
    a[j] = aj;
    c[j] = be[j] - mu * aj;
}

// ---------------- pool finalize ----------------

__global__ void k_bounds(const int* __restrict__ batch, int* __restrict__ gstart) {
    int g = threadIdx.x;
    if (g <= GN) {
        int lo = 0, hi = NN;
        while (lo < hi) {
            int mid = (lo + hi) >> 1;
            if (batch[mid] < g) lo = mid + 1; else hi = mid;
        }
        gstart[g] = lo;
    }
}

__global__ void k_poolfin(float* __restrict__ pooled, const int* __restrict__ gstart) {
    int idx = blockIdx.x * blockDim.x + threadIdx.x;
    if (idx < GN * HD) {
        int g = idx >> 8;
        float c = (float)max(gstart[g + 1] - gstart[g], 1);
        pooled[idx] /= c;
    }
}

// ---------------- MLP head ----------------

__global__ __launch_bounds__(256) void k_head1(const float* __restrict__ pooled,
                                               const float* __restrict__ actions,
                                               const float* __restrict__ fW1,
                                               const float* __restrict__ fb1,
                                               float* __restrict__ z1) {
    int g = blockIdx.x, j = threadIdx.x;
    float acc = fb1[j];
    for (int k = 0; k < HD; ++k)
        acc = fmaf(pooled[g * HD + k], fW1[k * HD + j], acc);
    for (int k = 0; k < AD; ++k)
        acc = fmaf(actions[k], fW1[(HD + k) * HD + j], acc);
    z1[g * HD + j] = fmaxf(acc, 0.f);
}

__global__ __launch_bounds__(256) void k_headbn(float* __restrict__ z1,
                                                const float* __restrict__ g3,
                                                const float* __restrict__ be3) {
    int j = threadIdx.x;
    float s = 0.f, q = 0.f;
    for (int g = 0; g < GN; ++g) {
        float v = z1[g * HD + j];
        s += v;
        q = fmaf(v, v, q);
    }
    float mu = s * (1.0f / GN);
    float var = q * (1.0f / GN) - mu * mu;
    float rs = rsqrtf(var + BN_EPS);
    float ga = g3[j], be = be3[j];
    for (int g = 0; g < GN; ++g)
        z1[g * HD + j] = fmaf((z1[g * HD + j] - mu) * rs, ga, be);
}

__global__ __launch_bounds__(128) void k_head2(const float* __restrict__ z1,
                                               const float* __restrict__ fW2,
                                               const float* __restrict__ fb2,
                                               float* __restrict__ z2) {
    int g = blockIdx.x, j = threadIdx.x;
    float acc = fb2[j];
    for (int k = 0; k < HD; ++k)
        acc = fmaf(z1[g * HD + k], fW2[k * (HD / 2) + j], acc);
    z2[g * (HD / 2) + j] = fmaxf(acc, 0.f);
}

__global__ __launch_bounds__(64) void k_head3(const float* __restrict__ z2,
                                              const float* __restrict__ fW3,
                                              const float* __restrict__ fb3,
                                              float* __restrict__ out) {
    int g = threadIdx.x;
    if (g < GN) {
        float acc = fb3[0];
        for (int k = 0; k < HD / 2; ++k)
            acc = fmaf(z2[g * (HD / 2) + k], fW3[k], acc);
        out[g] = acc;
    }
}

// ---------------- launch ----------------

static inline size_t align256(size_t x) { return (x + 255) & ~(size_t)255; }

extern "C" void kernel_launch(void* const* d_in, const int* in_sizes, int n_in,
                              void* d_out, int out_size, void* d_ws, size_t ws_size,
                              hipStream_t stream) {
    const float* x       = (const float*)d_in[0];
    const int*   ei      = (const int*)d_in[1];
    const int*   batch   = (const int*)d_in[2];
    const float* actions = (const float*)d_in[3];
    const float* W1 = (const float*)d_in[4];
    const float* b1 = (const float*)d_in[5];
    const float* W2 = (const float*)d_in[6];
    const float* b2 = (const float*)d_in[7];
    const float* W3 = (const float*)d_in[8];
    const float* b3 = (const float*)d_in[9];
    const float* g1  = (const float*)d_in[10];
    const float* be1 = (const float*)d_in[11];
    const float* g2  = (const float*)d_in[12];
    const float* be2 = (const float*)d_in[13];
    const float* g3  = (const float*)d_in[14];
    const float* be3 = (const float*)d_in[15];
    const float* fW1 = (const float*)d_in[16];
    const float* fb1 = (const float*)d_in[17];
    const float* fW2 = (const float*)d_in[18];
    const float* fb2 = (const float*)d_in[19];
    const float* fW3 = (const float*)d_in[20];
    const float* fb3 = (const float*)d_in[21];
    float* out = (float*)d_out;

    const int* esrc = ei;
    const int* edst = ei + NE;

    // workspace carve
    char* p = (char*)d_ws;
    size_t off = 0;
    auto carve = [&](size_t bytes) { void* r = p + off; off = align256(off + bytes); return r; };
    unsigned* xb   = (unsigned*)carve((size_t)4 * NP1 * 16 * 4);
    unsigned* xa   = (unsigned*)carve((size_t)4 * NP1 * 16 * 4);
    unsigned* tbuf = (unsigned*)carve((size_t)8 * NP1 * 16 * 4);
    unsigned* ah   = (unsigned*)carve((size_t)8 * NP1 * 16 * 4);
    float* dis     = (float*)carve((size_t)NP1 * 4);
    float* rdis    = (float*)carve((size_t)NN * 4);
    int*   counts  = (int*)carve((size_t)NN * 4);
    int*   rowptr  = (int*)carve((size_t)(NN + 1) * 4);
    int*   fill    = (int*)carve((size_t)NN * 4);
    unsigned short* csru = (unsigned short*)carve((size_t)(NE + NN) * 2);
    float* dsum    = (float*)carve((size_t)NN * 4);
    int*   bsum    = (int*)carve(64 * 4);
    float* pooled  = (float*)carve((size_t)GN * HD * 4);
    int*   gstart  = (int*)carve((size_t)(GN + 1) * 4);
    float* stats   = (float*)carve(2 * HD * 4);
    float* affa    = (float*)carve(HD * 4);
    float* affc    = (float*)carve(HD * 4);
    float* z1      = (float*)carve((size_t)GN * HD * 4);
    float* z2      = (float*)carve((size_t)GN * (HD / 2) * 4);
    unsigned short* W1t = (unsigned short*)carve((size_t)FD * HD * 2);
    unsigned short* W2t = (unsigned short*)carve((size_t)HD * HD * 2);
    unsigned short* W3t = (unsigned short*)carve((size_t)HD * HD * 2);
    (void)ws_size;

    const int TB = 256;
    const int ebk = (NE + TB - 1) / TB;
    const int nbk = (NN + TB - 1) / TB;
    const int scanblk = (NN + 1023) / 1024;
    const int mmg = (NN + 127) / 128;       // 391
    const int ngrp = NN / 16;               // 3125

    // weight casts
    k_castW<<<(FD * HD + 255) / 256, 256, 0, stream>>>(W1, W1t, FD);
    k_castW<<<(HD * HD + 255) / 256, 256, 0, stream>>>(W2, W2t, HD);
    k_castW<<<(HD * HD + 255) / 256, 256, 0, stream>>>(W3, W3t, HD);

    // degree + CSR (ushort, even-padded rows)
    hipMemsetAsync(counts, 0, (size_t)NN * 4, stream);
    k_deg<<<ebk, TB, 0, stream>>>(edst, counts);
    k_dis<<<nbk, TB, 0, stream>>>(counts, dis, rdis);
    k_scan1<<<scanblk, 1024, 0, stream>>>(counts, rowptr, bsum);
    k_scan2<<<1, 64, 0, stream>>>(bsum, rowptr, scanblk);
    k_scan3<<<nbk, TB, 0, stream>>>(rowptr, bsum);
    hipMemsetAsync(fill, 0, (size_t)NN * 4, stream);
    k_csr<<<ebk, TB, 0, stream>>>(esrc, edst, rowptr, fill, csru);
    k_pad<<<nbk, TB, 0, stream>>>(counts, rowptr, csru);
    k_dsum<<<nbk, TB, 0, stream>>>(rowptr, csru, dis, dsum);

    // input cast + zero pad rows
    k_castx<<<(NN * (FD / 2) + 255) / 256, 256, 0, stream>>>(x, dis, xb);
    k_zrow<<<1, 192, 0, stream>>>(xb, tbuf);

    // layer 1: agg(x') -> GEMM(+b1,relu,*dis, fused stats) -> t1'; affine
    hipMemsetAsync(stats, 0, 2 * HD * 4, stream);
    k_aggc<4, false><<<4 * ngrp, TB, 0, stream>>>(xb, rowptr, csru, dis,
                                                  nullptr, nullptr, nullptr, xa);
    k_mmf<FD, EPI_STATS><<<mmg, TB, 0, stream>>>(xa, W1t, b1, dis, (unsigned short*)tbuf,
                                                 nullptr, nullptr, stats);
    k_affine<<<1, HD, 0, stream>>>(stats, g1, be1, affa, affc);

    // layer 2: aggBN(t1') -> GEMM(+b2,relu,*dis, fused stats) -> t2'; affine
    hipMemsetAsync(stats, 0, 2 * HD * 4, stream);
    k_aggc<8, true><<<8 * ngrp, TB, 0, stream>>>(tbuf, rowptr, csru, dis,
                                                 affa, affc, dsum, ah);
    k_mmf<HD, EPI_STATS><<<mmg, TB, 0, stream>>>(ah, W2t, b2, dis, (unsigned short*)tbuf,
                                                 nullptr, nullptr, stats);
    k_affine<<<1, HD, 0, stream>>>(stats, g2, be2, affa, affc);

    // layer 3: aggBN(t2') -> GEMM(+b3,relu, fused pool)
    hipMemsetAsync(pooled, 0, (size_t)GN * HD * 4, stream);
    k_aggc<8, true><<<8 * ngrp, TB, 0, stream>>>(tbuf, rowptr, csru, dis,
                                                 affa, affc, dsum, ah);
    k_mmf<HD, EPI_POOL><<<mmg, TB, 0, stream>>>(ah, W3t, b3, dis, nullptr,
                                                batch, pooled, nullptr);

    // pool finalize
    k_bounds<<<1, 64, 0, stream>>>(batch, gstart);
    k_poolfin<<<(GN * HD + TB - 1) / TB, TB, 0, stream>>>(pooled, gstart);

    // head
    k_head1<<<GN, TB, 0, stream>>>(pooled, actions, fW1, fb1, z1);
    k_headbn<<<1, TB, 0, stream>>>(z1, g3, be3);
    k_head2<<<GN, 128, 0, stream>>>(z1, fW2, fb2, z2);
    k_head3<<<1, 64, 0, stream>>>(z2, fW3, fb3, out);
}